// Round 7
// baseline (549.781 us; speedup 1.0000x reference)
//
#include <hip/hip_runtime.h>
#include <cstddef>

#define NTOK 2048
#define BDIM 4
#define DIM 256
#define NHEAD 4
#define MROWS 8192
#define M2 16384                        // both descriptors batched
#define NMu ((size_t)MROWS * DIM)       // 2,097,152 elems (bf16 unit = 4 MB)

typedef unsigned short u16;
typedef __attribute__((ext_vector_type(8))) short short8;
typedef __attribute__((ext_vector_type(4))) float f32x4;

__device__ __forceinline__ u16 f2bf(float x) {
  union { float f; unsigned u; } c; c.f = x;
  unsigned r = c.u + 0x7FFFu + ((c.u >> 16) & 1u);
  return (u16)(r >> 16);
}
__device__ __forceinline__ float bf2f(u16 u) {
  union { unsigned u; float f; } c; c.u = ((unsigned)u) << 16;
  return c.f;
}

__device__ __forceinline__ void glds16(const void* g, void* l) {
  __builtin_amdgcn_global_load_lds(
      (const __attribute__((address_space(1))) unsigned int*)g,
      (__attribute__((address_space(3))) unsigned int*)l, 16, 0, 0);
}

// ---------------------------------------------------------------------------
// bf16 MFMA GEMM, 128x128 tile. Y = (A @ W^T + bias)*oscale, with:
//  - A split at kSplit between A/A2 (concat inputs)
//  - N split at nsplit: bias0/os0/Yb0 for cols<nsplit, bias1/os1/Yb1 after
// ---------------------------------------------------------------------------
__global__ __launch_bounds__(256) void gemm_bf16_kernel(
    const u16* __restrict__ A, int lda,
    const u16* __restrict__ A2, int lda2, int kSplit,
    const u16* __restrict__ W,
    const float* __restrict__ bias0, const float* __restrict__ bias1,
    int nsplit, float os0, float os1,
    u16* __restrict__ Yb0, int ldy0,
    u16* __restrict__ Yb1, int ldy1,
    int K)
{
  __shared__ u16 As[128 * 32];
  __shared__ u16 Bs[128 * 32];
  const int t = threadIdx.x;
  const int m0 = blockIdx.y * 128, n0 = blockIdx.x * 128;
  const int r4 = t >> 2, c8 = (t & 3) * 8;
  const int lane = t & 63, w = t >> 6;
  const int cl = lane & 15, quad = lane >> 4;
  const int wm = (w >> 1) * 64, wn = (w & 1) * 64;

  f32x4 acc[4][4];
#pragma unroll
  for (int i = 0; i < 4; ++i)
#pragma unroll
    for (int j = 0; j < 4; ++j) acc[i][j] = (f32x4){0.f, 0.f, 0.f, 0.f};

  for (int k0 = 0; k0 < K; k0 += 32) {
    const u16* Ab; int la; int kk;
    if (k0 < kSplit) { Ab = A; la = lda; kk = k0; }
    else             { Ab = A2; la = lda2; kk = k0 - kSplit; }
    const u16* ag = Ab + (size_t)(m0 + r4) * la + kk + c8;
    const u16* bg = W + (size_t)(n0 + r4) * K + k0 + c8;
    __syncthreads();
    glds16(ag, &As[t * 8]);
    glds16(ag + (size_t)64 * la, &As[2048 + t * 8]);
    glds16(bg, &Bs[t * 8]);
    glds16(bg + (size_t)64 * K, &Bs[2048 + t * 8]);
    __syncthreads();

    short8 af[4], bfr[4];
#pragma unroll
    for (int i = 0; i < 4; ++i)
      af[i] = *(const short8*)&As[(wm + i * 16 + cl) * 32 + quad * 8];
#pragma unroll
    for (int i = 0; i < 4; ++i)
      bfr[i] = *(const short8*)&Bs[(wn + i * 16 + cl) * 32 + quad * 8];
#pragma unroll
    for (int mt = 0; mt < 4; ++mt)
#pragma unroll
      for (int nt = 0; nt < 4; ++nt)
        acc[mt][nt] = __builtin_amdgcn_mfma_f32_16x16x32_bf16(
            af[mt], bfr[nt], acc[mt][nt], 0, 0, 0);
  }

#pragma unroll
  for (int mt = 0; mt < 4; ++mt)
#pragma unroll
    for (int nt = 0; nt < 4; ++nt) {
      const int colg = n0 + wn + nt * 16 + cl;
      const bool first = colg < nsplit;
      const int c2 = first ? colg : colg - nsplit;
      const float bs = first ? bias0[c2] : bias1[c2];
      const float os = first ? os0 : os1;
      u16* yb = first ? Yb0 : Yb1;
      const int ly = first ? ldy0 : ldy1;
#pragma unroll
      for (int r = 0; r < 4; ++r) {
        const int rowg = m0 + wm + mt * 16 + quad * 4 + r;
        yb[(size_t)rowg * ly + c2] = f2bf((acc[mt][nt][r] + bs) * os);
      }
    }
}

// ---------------------------------------------------------------------------
// bf16 MFMA GEMM, 64x64 tile (N==256 GEMMs -> 1024 blocks = 4/CU).
// ---------------------------------------------------------------------------
__global__ __launch_bounds__(256) void gemm64_kernel(
    const u16* __restrict__ A, int lda,
    const u16* __restrict__ W,
    const float* __restrict__ bias,
    const u16* __restrict__ resb, int ldrb,
    float* __restrict__ Yf, int ldyf,
    u16* __restrict__ Yb, int ldyb,
    int K)
{
  __shared__ u16 As[64 * 32];
  __shared__ u16 Bs[64 * 32];
  const int t = threadIdx.x;
  const int m0 = blockIdx.y * 64, n0 = blockIdx.x * 64;
  const int r8 = t >> 2, c8 = (t & 3) * 8;
  const int lane = t & 63, w = t >> 6;
  const int cl = lane & 15, quad = lane >> 4;
  const int wm = (w >> 1) * 32, wn = (w & 1) * 32;

  f32x4 acc[2][2];
#pragma unroll
  for (int i = 0; i < 2; ++i)
#pragma unroll
    for (int j = 0; j < 2; ++j) acc[i][j] = (f32x4){0.f, 0.f, 0.f, 0.f};

  for (int k0 = 0; k0 < K; k0 += 32) {
    const u16* ag = A + (size_t)(m0 + r8) * lda + k0 + c8;
    const u16* bg = W + (size_t)(n0 + r8) * K + k0 + c8;
    __syncthreads();
    glds16(ag, &As[t * 8]);
    glds16(bg, &Bs[t * 8]);
    __syncthreads();

    short8 af[2], bfr[2];
#pragma unroll
    for (int i = 0; i < 2; ++i)
      af[i] = *(const short8*)&As[(wm + i * 16 + cl) * 32 + quad * 8];
#pragma unroll
    for (int j = 0; j < 2; ++j)
      bfr[j] = *(const short8*)&Bs[(wn + j * 16 + cl) * 32 + quad * 8];
#pragma unroll
    for (int mt = 0; mt < 2; ++mt)
#pragma unroll
      for (int nt = 0; nt < 2; ++nt)
        acc[mt][nt] = __builtin_amdgcn_mfma_f32_16x16x32_bf16(
            af[mt], bfr[nt], acc[mt][nt], 0, 0, 0);
  }

#pragma unroll
  for (int mt = 0; mt < 2; ++mt)
#pragma unroll
    for (int nt = 0; nt < 2; ++nt) {
      const int colg = n0 + wn + nt * 16 + cl;
      const float bs = bias[colg];
#pragma unroll
      for (int r = 0; r < 4; ++r) {
        const int rowg = m0 + wm + mt * 16 + quad * 4 + r;
        float v = acc[mt][nt][r] + bs;
        if (resb) v += bf2f(resb[(size_t)rowg * ldrb + colg]);
        if (Yf) Yf[(size_t)rowg * ldyf + colg] = v;
        if (Yb) Yb[(size_t)rowg * ldyb + colg] = f2bf(v);
      }
    }
}

// ---------------------------------------------------------------------------
// Weight fusion: W1f[n][k] = k<256 ? W1[n][k] : sum_m W1[n][256+m]*Wo[m][k-256]
// b1f[n] = b1[n] + sum_m W1[n][256+m]*bo[m].  All fp32 math, bf16 output.
// ---------------------------------------------------------------------------
__global__ __launch_bounds__(256) void wfuse_kernel(
    const float* __restrict__ W1, const float* __restrict__ Wo,
    const float* __restrict__ b1, const float* __restrict__ bo,
    const float* __restrict__ cW1, const float* __restrict__ cWo,
    const float* __restrict__ cb1, const float* __restrict__ cbo,
    u16* __restrict__ W1f, u16* __restrict__ cW1f,
    float* __restrict__ b1f, float* __restrict__ cb1f)
{
  const int n = blockIdx.x, sel = blockIdx.y;
  const float* Ws = sel ? cW1 : W1;
  const float* Wos = sel ? cWo : Wo;
  u16* out = sel ? cW1f : W1f;
  __shared__ float rowh[256];
  const int t = threadIdx.x;
  rowh[t] = Ws[(size_t)n * 512 + 256 + t];
  out[(size_t)n * 512 + t] = f2bf(Ws[(size_t)n * 512 + t]);
  __syncthreads();
  float acc = 0.f;
  for (int m = 0; m < 256; ++m) acc += rowh[m] * Wos[(size_t)m * 256 + t];
  out[(size_t)n * 512 + 256 + t] = f2bf(acc);
  if (t == 0) {
    const float* bos = sel ? cbo : bo;
    const float* b1s = sel ? cb1 : b1;
    float a = b1s[n];
    for (int m = 0; m < 256; ++m) a += rowh[m] * bos[m];
    (sel ? cb1f : b1f)[n] = a;
  }
}

// ---------------------------------------------------------------------------
// RoPE batched. qkv (M2,768) -> Qu (scaled 0.125*log2e), Ku, Vu bf16 (M2,256).
// ---------------------------------------------------------------------------
__global__ __launch_bounds__(256) void rope_repack_kernel(
    const u16* __restrict__ qkv, const float* __restrict__ enc0,
    const float* __restrict__ enc1,
    u16* __restrict__ Q, u16* __restrict__ K, u16* __restrict__ V)
{
  const int idx = blockIdx.x * blockDim.x + threadIdx.x;  // < M2*4*32
  const int i = idx & 31;
  const int h = (idx >> 5) & 3;
  const int m = idx >> 7;
  const int half = m >> 13;
  const int lm = m & (MROWS - 1);
  const float* enc = half ? enc1 : enc0;
  const u16* src = qkv + (size_t)m * 768 + h * 192 + i * 6;
  const unsigned a0 = *(const unsigned*)(src);
  const unsigned a1 = *(const unsigned*)(src + 2);
  const unsigned a2 = *(const unsigned*)(src + 4);
  const float q0 = bf2f((u16)a0), k0 = bf2f((u16)(a0 >> 16));
  const float v0 = bf2f((u16)a1), q1 = bf2f((u16)(a1 >> 16));
  const float k1 = bf2f((u16)a2), v1 = bf2f((u16)(a2 >> 16));
  const float c = enc[(size_t)lm * 64 + 2 * i];
  const float s = enc[(size_t)MROWS * 64 + (size_t)lm * 64 + 2 * i];
  const float QSC = 0.18033688011112042f;   // 0.125 * log2(e) -> exp2 softmax
  const size_t o = (size_t)m * 256 + h * 64 + 2 * i;
  *(unsigned*)(Q + o) = (unsigned)f2bf((q0 * c - q1 * s) * QSC) |
                        ((unsigned)f2bf((q1 * c + q0 * s) * QSC) << 16);
  *(unsigned*)(K + o) = (unsigned)f2bf(k0 * c - k1 * s) |
                        ((unsigned)f2bf(k1 * c + k0 * s) << 16);
  *(unsigned*)(V + o) = (unsigned)f2bf(v0) | ((unsigned)f2bf(v1) << 16);
}

// bf16 unheads (M2,256) -> bf16 transposed head-major (8,H,64,2048)
__global__ __launch_bounds__(256) void transpose_v_kernel(
    const u16* __restrict__ in, u16* __restrict__ out)
{
  __shared__ u16 Tl[64][72];
  const int bz = blockIdx.z, h = blockIdx.y;
  const int n0 = blockIdx.x * 64;
  const int t = threadIdx.x;
  {
    const int row = t >> 2, c16 = (t & 3) * 16;
    const u16* src = in + (size_t)(bz * NTOK + n0 + row) * 256 + h * 64 + c16;
    *(uint4*)&Tl[row][c16] = *(const uint4*)src;
    *(uint4*)&Tl[row][c16 + 8] = *(const uint4*)(src + 8);
  }
  __syncthreads();
  const int d = t >> 2, qr = t & 3;
  union { u16 u[16]; uint4 v[2]; } pk;
#pragma unroll
  for (int j = 0; j < 16; ++j) pk.u[j] = Tl[qr * 16 + j][d];
  u16* dst = out + ((size_t)((bz * NHEAD + h) * 64 + d)) * NTOK + n0 + qr * 16;
  *(uint4*)dst = pk.v[0];
  *(uint4*)(dst + 8) = pk.v[1];
}

// ---------------------------------------------------------------------------
// MFMA flash attention v4: barrier-free K-loop. K and V^T fragments are
// loaded DIRECTLY from global (each wave-load = 16 fully-consumed 64B lines;
// L1/L2 serve the 4-wave + 16-block reuse). Only the P C->B layout transform
// round-trips through wave-private LDS rows -> no __syncthreads in the loop.
// Wave-uniform running max -> uniform alpha -> rescale skipped when max
// unchanged. grid (16, 32, 2), block 256 = 4 waves, 32 q/wave. LDS 18.4 KB.
// ---------------------------------------------------------------------------
__global__ __launch_bounds__(256, 4) void attn4_kernel(
    const u16* __restrict__ Qb, const u16* __restrict__ Kb,
    const u16* __restrict__ Vtb,
    u16* __restrict__ Po, float* __restrict__ Pm, float* __restrict__ Pl,
    int cross)
{
  __shared__ u16 QPs[128 * 72];  // Q tile at start, then per-wave P region
  const int y = blockIdx.y, z = blockIdx.z;
  const int h2 = y >> 4, b = (y >> 2) & 3, h = y & 3;
  const int kh = cross ? (1 - h2) : h2;
  const int qrowbase = (h2 * 4 + b) * NTOK;
  const int krowbase = (kh * 4 + b) * NTOK + z * 1024;
  const int vz = kh * 4 + b;
  const int n0 = blockIdx.x * 128;
  const int t = threadIdx.x, lane = t & 63, w = t >> 6;
  const int cl = lane & 15, quad = lane >> 4;

  // stage Q tile (128 x 64 bf16) once
  {
    const int row = t >> 1, c32 = (t & 1) * 32;
    const u16* src = Qb + (size_t)(qrowbase + n0 + row) * 256 + h * 64 + c32;
    uint4 v0 = *(const uint4*)src;
    uint4 v1 = *(const uint4*)(src + 8);
    uint4 v2 = *(const uint4*)(src + 16);
    uint4 v3 = *(const uint4*)(src + 24);
    u16* d = &QPs[row * 72 + c32];
    *(uint4*)d = v0; *(uint4*)(d + 8) = v1;
    *(uint4*)(d + 16) = v2; *(uint4*)(d + 24) = v3;
  }
  __syncthreads();
  const int q0 = w * 32;
  short8 bq[2][2];
#pragma unroll
  for (int c = 0; c < 2; ++c) {
    bq[c][0] = *(const short8*)&QPs[(q0 + c * 16 + cl) * 72 + quad * 8];
    bq[c][1] = *(const short8*)&QPs[(q0 + c * 16 + cl) * 72 + quad * 8 + 32];
  }

  float m_r = -1e30f;            // wave-uniform running max
  float l_r[2] = {0.f, 0.f};
  f32x4 o[2][4];
#pragma unroll
  for (int c = 0; c < 2; ++c)
#pragma unroll
    for (int i = 0; i < 4; ++i) o[c][i] = (f32x4){0.f, 0.f, 0.f, 0.f};

  // direct-global fragment base pointers (lane-resolved)
  const u16* Kp = Kb + (size_t)(krowbase + cl) * 256 + h * 64 + quad * 8;
  const u16* Vp = Vtb + ((size_t)(vz * NHEAD + h) * 64 + cl) * 2048 + z * 1024 + quad * 8;

  for (int tile = 0; tile < 16; ++tile) {
    // S^T strip: 64 keys x 32 q; K A-frags straight from global
    f32x4 sf[2][4];
#pragma unroll
    for (int kb = 0; kb < 4; ++kb) {
      const u16* ka = Kp + (size_t)(tile * 64 + kb * 16) * 256;
      short8 ak0 = *(const short8*)ka;
      short8 ak1 = *(const short8*)(ka + 32);
#pragma unroll
      for (int c = 0; c < 2; ++c) {
        f32x4 acc = (f32x4){0.f, 0.f, 0.f, 0.f};
        acc = __builtin_amdgcn_mfma_f32_16x16x32_bf16(ak0, bq[c][0], acc, 0, 0, 0);
        acc = __builtin_amdgcn_mfma_f32_16x16x32_bf16(ak1, bq[c][1], acc, 0, 0, 0);
        sf[c][kb] = acc;
      }
    }

    // wave-uniform max
    float mx = sf[0][0][0];
#pragma unroll
    for (int c = 0; c < 2; ++c)
#pragma unroll
      for (int kb = 0; kb < 4; ++kb)
#pragma unroll
        for (int r = 0; r < 4; ++r) mx = fmaxf(mx, sf[c][kb][r]);
    mx = fmaxf(mx, __shfl_xor(mx, 1));
    mx = fmaxf(mx, __shfl_xor(mx, 2));
    mx = fmaxf(mx, __shfl_xor(mx, 4));
    mx = fmaxf(mx, __shfl_xor(mx, 8));
    mx = fmaxf(mx, __shfl_xor(mx, 16));
    mx = fmaxf(mx, __shfl_xor(mx, 32));
    const bool newmax = mx > m_r;
    const float mn = newmax ? mx : m_r;
    const float alpha = exp2f(m_r - mn);
    m_r = mn;

    // p = exp2(s - m), per-column row sums
#pragma unroll
    for (int c = 0; c < 2; ++c) {
      float rs = 0.f;
#pragma unroll
      for (int kb = 0; kb < 4; ++kb)
#pragma unroll
        for (int r = 0; r < 4; ++r) {
          const float p = exp2f(sf[c][kb][r] - mn);
          sf[c][kb][r] = p; rs += p;
        }
      rs += __shfl_xor(rs, 16);
      rs += __shfl_xor(rs, 32);
      l_r[c] = l_r[c] * alpha + rs;
      // P rows (q-major) into wave-private LDS region
#pragma unroll
      for (int kb = 0; kb < 4; ++kb) {
        unsigned d0 = __builtin_amdgcn_perm(__float_as_uint(sf[c][kb][1]),
                                            __float_as_uint(sf[c][kb][0]), 0x07060302u);
        unsigned d1 = __builtin_amdgcn_perm(__float_as_uint(sf[c][kb][3]),
                                            __float_as_uint(sf[c][kb][2]), 0x07060302u);
        uint2 pk; pk.x = d0; pk.y = d1;
        *(uint2*)&QPs[(q0 + c * 16 + cl) * 72 + kb * 16 + quad * 4] = pk;
      }
    }
    if (newmax) {   // wave-uniform branch: rescale only on new max
#pragma unroll
      for (int c = 0; c < 2; ++c)
#pragma unroll
        for (int db = 0; db < 4; ++db) o[c][db] *= alpha;
    }

    // O^T += V^T P^T; V A-frags straight from global, P B-frags from LDS
    short8 bp[2][2];
#pragma unroll
    for (int c = 0; c < 2; ++c) {
      bp[c][0] = *(const short8*)&QPs[(q0 + c * 16 + cl) * 72 + quad * 8];
      bp[c][1] = *(const short8*)&QPs[(q0 + c * 16 + cl) * 72 + quad * 8 + 32];
    }
#pragma unroll
    for (int db = 0; db < 4; ++db) {
      const u16* va = Vp + (size_t)db * 16 * 2048 + tile * 64;
      short8 av0 = *(const short8*)va;
      short8 av1 = *(const short8*)(va + 32);
#pragma unroll
      for (int c = 0; c < 2; ++c) {
        o[c][db] = __builtin_amdgcn_mfma_f32_16x16x32_bf16(av0, bp[c][0], o[c][db], 0, 0, 0);
        o[c][db] = __builtin_amdgcn_mfma_f32_16x16x32_bf16(av1, bp[c][1], o[c][db], 0, 0, 0);
      }
    }
  }

  // store partials
#pragma unroll
  for (int c = 0; c < 2; ++c) {
    const int rp = z * 65536 + y * 2048 + n0 + q0 + c * 16 + cl;
#pragma unroll
    for (int db = 0; db < 4; ++db) {
      ushort4 st;
      st.x = f2bf(o[c][db][0]); st.y = f2bf(o[c][db][1]);
      st.z = f2bf(o[c][db][2]); st.w = f2bf(o[c][db][3]);
      *(ushort4*)(Po + (size_t)rp * 64 + db * 16 + quad * 4) = st;
    }
    if (quad == 0) { Pm[rp] = m_r; Pl[rp] = l_r[c]; }
  }
}

// combine the 2 K-split partials (exp2 domain) -> bf16 unheads output
__global__ __launch_bounds__(256) void attn_combine_kernel(
    const u16* __restrict__ Po, const float* __restrict__ Pm,
    const float* __restrict__ Pl, u16* __restrict__ Ou)
{
  const int rowi = blockIdx.x * 4 + (threadIdx.x >> 6);
  const int lane = threadIdx.x & 63;
  const float m0 = Pm[rowi], m1 = Pm[65536 + rowi];
  const float l0 = Pl[rowi], l1 = Pl[65536 + rowi];
  const float M = fmaxf(m0, m1);
  const float e0 = exp2f(m0 - M), e1 = exp2f(m1 - M);
  const float inv = 1.f / (e0 * l0 + e1 * l1);
  const float o0 = bf2f(Po[(size_t)rowi * 64 + lane]);
  const float o1 = bf2f(Po[(size_t)65536 * 64 + (size_t)rowi * 64 + lane]);
  const float val = (e0 * o0 + e1 * o1) * inv;
  const int y = rowi >> 11, q = rowi & 2047;
  const int bz = y >> 2, h = y & 3;
  Ou[(size_t)(bz * NTOK + q) * 256 + h * 64 + lane] = f2bf(val);
}

// ---------------------------------------------------------------------------
// LayerNorm + exact GELU, bf16 in (M2,512) -> bf16 out
// ---------------------------------------------------------------------------
__global__ __launch_bounds__(256) void ln_gelu_kernel(
    const u16* __restrict__ Hm, const float* __restrict__ g,
    const float* __restrict__ be, u16* __restrict__ out)
{
  const int rowi = blockIdx.x * 4 + (threadIdx.x >> 6);
  const int lane = threadIdx.x & 63;
  const u16* row = Hm + (size_t)rowi * 512 + lane * 8;
  u16* orow = out + (size_t)rowi * 512 + lane * 8;
  uint4 raw = *(const uint4*)row;
  float x[8];
  const unsigned* rw = (const unsigned*)&raw;
#pragma unroll
  for (int i = 0; i < 4; ++i) {
    x[2 * i]     = bf2f((u16)rw[i]);
    x[2 * i + 1] = bf2f((u16)(rw[i] >> 16));
  }
  float s = 0.f;
#pragma unroll
  for (int i = 0; i < 8; ++i) s += x[i];
#pragma unroll
  for (int off = 32; off; off >>= 1) s += __shfl_xor(s, off);
  const float mean = s * (1.f / 512.f);
  float s2 = 0.f;
#pragma unroll
  for (int i = 0; i < 8; ++i) { const float d = x[i] - mean; s2 += d * d; }
#pragma unroll
  for (int off = 32; off; off >>= 1) s2 += __shfl_xor(s2, off);
  const float rstd = rsqrtf(s2 * (1.f / 512.f) + 1e-5f);
  unsigned ov[4];
#pragma unroll
  for (int i = 0; i < 4; ++i) {
    const int c = lane * 8 + 2 * i;
    const float y0 = (x[2 * i] - mean) * rstd * g[c] + be[c];
    const float y1 = (x[2 * i + 1] - mean) * rstd * g[c + 1] + be[c + 1];
    const float g0 = 0.5f * y0 * (1.f + erff(y0 * 0.70710678118654752f));
    const float g1 = 0.5f * y1 * (1.f + erff(y1 * 0.70710678118654752f));
    ov[i] = (unsigned)f2bf(g0) | ((unsigned)f2bf(g1) << 16);
  }
  *(uint4*)orow = *(uint4*)ov;
}

// ---------------------------------------------------------------------------
// pack everything fp32 -> bf16: 5 weight mats (589824 elems) + 2 descs.
// ---------------------------------------------------------------------------
__global__ __launch_bounds__(256) void pack_all_kernel(
    const float* w0, const float* w1, const float* w2, const float* w3,
    const float* w4, const float* d0, const float* d1,
    u16* __restrict__ wb, u16* __restrict__ descb)
{
  const size_t idx4 = ((size_t)blockIdx.x * 256 + threadIdx.x) * 4;
  const float* src; u16* dst; size_t off;
  if (idx4 < 589824) {
    off = idx4; dst = wb + idx4;
    if      (idx4 < 196608) { src = w0; }
    else if (idx4 < 327680) { src = w1; off -= 196608; }
    else if (idx4 < 393216) { src = w2; off -= 327680; }
    else if (idx4 < 458752) { src = w3; off -= 393216; }
    else                    { src = w4; off -= 458752; }
  } else {
    size_t o = idx4 - 589824;
    dst = descb + o;
    if (o < NMu) { src = d0; off = o; }
    else         { src = d1; off = o - NMu; }
  }
  float4 v = *(const float4*)(src + off);
  ushort4 ov;
  ov.x = f2bf(v.x); ov.y = f2bf(v.y); ov.z = f2bf(v.z); ov.w = f2bf(v.w);
  *(ushort4*)dst = ov;
}

// ---------------------------------------------------------------------------
extern "C" void kernel_launch(void* const* d_in, const int* in_sizes, int n_in,
                              void* d_out, int out_size, void* d_ws, size_t ws_size,
                              hipStream_t stream) {
  const float* desc0  = (const float*)d_in[0];
  const float* desc1  = (const float*)d_in[1];
  const float* enc0   = (const float*)d_in[2];
  const float* enc1   = (const float*)d_in[3];
  const float* s_Wqkv = (const float*)d_in[4];
  const float* s_bqkv = (const float*)d_in[5];
  const float* s_Wout = (const float*)d_in[6];
  const float* s_bout = (const float*)d_in[7];
  const float* s_W1   = (const float*)d_in[8];
  const float* s_b1   = (const float*)d_in[9];
  const float* s_g    = (const float*)d_in[10];
  const float* s_be   = (const float*)d_in[11];
  const float* s_W2   = (const float*)d_in[12];
  const float* s_b2   = (const float*)d_in[13];
  const float* c_Wqk  = (const float*)d_in[14];
  const float* c_bqk  = (const float*)d_in[15];
  const float* c_Wv   = (const float*)d_in[16];
  const float* c_bv   = (const float*)d_in[17];
  const float* c_Wo   = (const float*)d_in[18];
  const float* c_bo   = (const float*)d_in[19];
  const float* c_W1   = (const float*)d_in[20];
  const float* c_b1   = (const float*)d_in[21];
  const float* c_g    = (const float*)d_in[22];
  const float* c_be   = (const float*)d_in[23];
  const float* c_W2   = (const float*)d_in[24];
  const float* c_b2   = (const float*)d_in[25];

  u16* U = (u16*)d_ws;
  u16* descb = U + 0 * NMu;             // [all]
  u16* qkvb  = U + 2 * NMu;             // 6u, phase A only
  u16* ctxb  = U + 2 * NMu;             // 2u, combine out (self B / cross E)
  u16* Qu    = U + 8 * NMu;             // self Q / cross qkb
  u16* Ku    = U + 10 * NMu;            // self K / cross vb
  u16* Vu    = U + 12 * NMu;            // self V staging
  u16* Vt    = U + 14 * NMu;            // transposed V
  u16* hbufb = U + 12 * NMu;            // 4u ffn hidden (after attn)
  u16* Po    = U + 16 * NMu;            // 4u attn partials
  u16* hb2   = U + 16 * NMu;            // 4u ln out (after combine)
  float* Pm  = (float*)(U + 20 * NMu);
  float* Pl  = Pm + 2 * 65536;
  float* b1f = Pl + 2 * 65536;          // 512 fp32
  float* cb1f = b1f + 512;
  u16* s_b   = U + 21 * NMu;            // self outputs
  u16* wb    = U + 23 * NMu;

  u16* Wqkvb = wb;                      // 196608
  u16* W2b   = wb + 196608;             // 131072
  u16* cQKVb = wb + 327680;             // cWqk(65536) || cWv(65536)
  u16* cW2b  = wb + 458752;             // 131072
  u16* W1f   = wb + 589824;             // 262144 (fused self FFN1 weight)
  u16* cW1f  = wb + 851968;             // 262144

  float* outf = (float*)d_out;

  const dim3 attn_grid(NTOK / 128, 32, 2);
  const dim3 tv_grid(NTOK / 64, NHEAD, 8);
  const int rope_blocks = (M2 * 128) / 256;
  const int lng_blocks  = M2 / 4;
  const int comb_blocks = 65536 / 4;
  const float csc = 0.42466090014400953f;  // 8^-0.5 * sqrt(log2 e)

  // 1. pack weights + descs
  hipLaunchKernelGGL(pack_all_kernel, dim3(4672), dim3(256), 0, stream,
                     s_Wqkv, s_W2, c_Wqk, c_Wv, c_W2, desc0, desc1, wb, descb);
  // 2. fold Wout->W1, cWo->cW1 (+bias folds)
  hipLaunchKernelGGL(wfuse_kernel, dim3(512, 2), dim3(256), 0, stream,
                     s_W1, s_Wout, s_b1, s_bout, c_W1, c_Wo, c_b1, c_bo,
                     W1f, cW1f, b1f, cb1f);

  // ---------------- self blocks (batched) ----------------
  // 3. qkv GEMM
  hipLaunchKernelGGL(gemm_bf16_kernel, dim3(6, 128), dim3(256), 0, stream,
                     descb, 256, (const u16*)nullptr, 0, 1 << 30, Wqkvb,
                     s_bqkv, (const float*)nullptr, 1 << 30, 1.f, 1.f,
                     qkvb, 768, (u16*)nullptr, 0, 256);
  // 4. rope
  hipLaunchKernelGGL(rope_repack_kernel, dim3(rope_blocks), dim3(256), 0, stream,
                     qkvb, enc0, enc1, Qu, Ku, Vu);
  // 5. transpose V
  hipLaunchKernelGGL(transpose_v_kernel, tv_grid, dim3(256), 0, stream, Vu, Vt);
  // 6/7. attention + combine
  hipLaunchKernelGGL(attn4_kernel, attn_grid, dim3(256), 0, stream,
                     Qu, Ku, Vt, Po, Pm, Pl, 0);
  hipLaunchKernelGGL(attn_combine_kernel, dim3(comb_blocks), dim3(256), 0, stream,
                     Po, Pm, Pl, ctxb);
  // 8. FFN1 (fused Wout): A=[descb | ctxb] @ W1f^T + b1f
  hipLaunchKernelGGL(gemm_bf16_kernel, dim3(4, 128), dim3(256), 0, stream,
                     descb, 256, ctxb, 256, 256, W1f,
                     b1f, (const float*)nullptr, 1 << 30, 1.f, 1.f,
                     hbufb, 512, (u16*)nullptr, 0, 512);
  // 9. LN + GELU
  hipLaunchKernelGGL(ln_gelu_kernel, dim3(lng_blocks), dim3(256), 0, stream,
                     hbufb, s_g, s_be, hb2);
  // 10. W2 + residual
  hipLaunchKernelGGL(gemm64_kernel, dim3(4, 256), dim3(256), 0, stream,
                     hb2, 512, W2b, s_b2, descb, 256,
                     (float*)nullptr, 0, s_b, 256, 512);

  // ---------------- cross block (batched) ----------------
  u16* qkb = Qu;
  u16* vb  = Ku;
  // 11. fused qk|v projection (per-half bias/scale/output)
  hipLaunchKernelGGL(gemm_bf16_kernel, dim3(4, 128), dim3(256), 0, stream,
                     s_b, 256, (const u16*)nullptr, 0, 1 << 30, cQKVb,
                     c_bqk, c_bv, 256, csc, 1.f,
                     qkb, 256, vb, 256, 256);
  // 12. transpose V
  hipLaunchKernelGGL(transpose_v_kernel, tv_grid, dim3(256), 0, stream, vb, Vt);
  // 13/14. attention + combine
  hipLaunchKernelGGL(attn4_kernel, attn_grid, dim3(256), 0, stream,
                     qkb, qkb, Vt, Po, Pm, Pl, 1);
  hipLaunchKernelGGL(attn_combine_kernel, dim3(comb_blocks), dim3(256), 0, stream,
                     Po, Pm, Pl, ctxb);
  // 15. FFN1 (fused cWo)
  hipLaunchKernelGGL(gemm_bf16_kernel, dim3(4, 128), dim3(256), 0, stream,
                     s_b, 256, ctxb, 256, 256, cW1f,
                     cb1f, (const float*)nullptr, 1 << 30, 1.f, 1.f,
                     hbufb, 512, (u16*)nullptr, 0, 512);
  // 16. LN + GELU
  hipLaunchKernelGGL(ln_gelu_kernel, dim3(lng_blocks), dim3(256), 0, stream,
                     hbufb, c_g, c_be, hb2);
  // 17. W2 + residual -> fp32 output
  hipLaunchKernelGGL(gemm64_kernel, dim3(4, 256), dim3(256), 0, stream,
                     hb2, 512, cW2b, c_b2, s_b, 256,
                     outf, 256, (u16*)nullptr, 0, 512);
}

// Round 8
// 430.898 us; speedup vs baseline: 1.2759x; 1.2759x over previous
//
#include <hip/hip_runtime.h>
#include <cstddef>

#define NTOK 2048
#define BDIM 4
#define DIM 256
#define NHEAD 4
#define MROWS 8192
#define M2 16384                        // both descriptors batched
#define NMu ((size_t)MROWS * DIM)       // 2,097,152 elems (bf16 unit = 4 MB)

typedef unsigned short u16;
typedef __attribute__((ext_vector_type(8))) short short8;
typedef __attribute__((ext_vector_type(4))) float f32x4;

#if __has_builtin(__builtin_amdgcn_exp2f)
#define EXP2(x) __builtin_amdgcn_exp2f(x)
#else
#define EXP2(x) exp2f(x)
#endif

__device__ __forceinline__ u16 f2bf(float x) {
  union { float f; unsigned u; } c; c.f = x;
  unsigned r = c.u + 0x7FFFu + ((c.u >> 16) & 1u);
  return (u16)(r >> 16);
}
__device__ __forceinline__ float bf2f(u16 u) {
  union { unsigned u; float f; } c; c.u = ((unsigned)u) << 16;
  return c.f;
}

__device__ __forceinline__ void glds16(const void* g, void* l) {
  __builtin_amdgcn_global_load_lds(
      (const __attribute__((address_space(1))) unsigned int*)g,
      (__attribute__((address_space(3))) unsigned int*)l, 16, 0, 0);
}

// ---------------------------------------------------------------------------
// bf16 MFMA GEMM, 128x128 tile. Y = (A @ W^T + bias)*oscale, with:
//  - A split at kSplit between A/A2 (concat inputs)
//  - N split at nsplit: bias0/os0/Yb0 for cols<nsplit, bias1/os1/Yb1 after
// ---------------------------------------------------------------------------
__global__ __launch_bounds__(256) void gemm_bf16_kernel(
    const u16* __restrict__ A, int lda,
    const u16* __restrict__ A2, int lda2, int kSplit,
    const u16* __restrict__ W,
    const float* __restrict__ bias0, const float* __restrict__ bias1,
    int nsplit, float os0, float os1,
    u16* __restrict__ Yb0, int ldy0,
    u16* __restrict__ Yb1, int ldy1,
    int K)
{
  __shared__ u16 As[128 * 32];
  __shared__ u16 Bs[128 * 32];
  const int t = threadIdx.x;
  const int m0 = blockIdx.y * 128, n0 = blockIdx.x * 128;
  const int r4 = t >> 2, c8 = (t & 3) * 8;
  const int lane = t & 63, w = t >> 6;
  const int cl = lane & 15, quad = lane >> 4;
  const int wm = (w >> 1) * 64, wn = (w & 1) * 64;

  f32x4 acc[4][4];
#pragma unroll
  for (int i = 0; i < 4; ++i)
#pragma unroll
    for (int j = 0; j < 4; ++j) acc[i][j] = (f32x4){0.f, 0.f, 0.f, 0.f};

  for (int k0 = 0; k0 < K; k0 += 32) {
    const u16* Ab; int la; int kk;
    if (k0 < kSplit) { Ab = A; la = lda; kk = k0; }
    else             { Ab = A2; la = lda2; kk = k0 - kSplit; }
    const u16* ag = Ab + (size_t)(m0 + r4) * la + kk + c8;
    const u16* bg = W + (size_t)(n0 + r4) * K + k0 + c8;
    __syncthreads();
    glds16(ag, &As[t * 8]);
    glds16(ag + (size_t)64 * la, &As[2048 + t * 8]);
    glds16(bg, &Bs[t * 8]);
    glds16(bg + (size_t)64 * K, &Bs[2048 + t * 8]);
    __syncthreads();

    short8 af[4], bfr[4];
#pragma unroll
    for (int i = 0; i < 4; ++i)
      af[i] = *(const short8*)&As[(wm + i * 16 + cl) * 32 + quad * 8];
#pragma unroll
    for (int i = 0; i < 4; ++i)
      bfr[i] = *(const short8*)&Bs[(wn + i * 16 + cl) * 32 + quad * 8];
#pragma unroll
    for (int mt = 0; mt < 4; ++mt)
#pragma unroll
      for (int nt = 0; nt < 4; ++nt)
        acc[mt][nt] = __builtin_amdgcn_mfma_f32_16x16x32_bf16(
            af[mt], bfr[nt], acc[mt][nt], 0, 0, 0);
  }

#pragma unroll
  for (int mt = 0; mt < 4; ++mt)
#pragma unroll
    for (int nt = 0; nt < 4; ++nt) {
      const int colg = n0 + wn + nt * 16 + cl;
      const bool first = colg < nsplit;
      const int c2 = first ? colg : colg - nsplit;
      const float bs = first ? bias0[c2] : bias1[c2];
      const float os = first ? os0 : os1;
      u16* yb = first ? Yb0 : Yb1;
      const int ly = first ? ldy0 : ldy1;
#pragma unroll
      for (int r = 0; r < 4; ++r) {
        const int rowg = m0 + wm + mt * 16 + quad * 4 + r;
        yb[(size_t)rowg * ly + c2] = f2bf((acc[mt][nt][r] + bs) * os);
      }
    }
}

// ---------------------------------------------------------------------------
// bf16 MFMA GEMM, 64x64 tile (N==256 GEMMs -> 1024 blocks = 4/CU).
// ---------------------------------------------------------------------------
__global__ __launch_bounds__(256) void gemm64_kernel(
    const u16* __restrict__ A, int lda,
    const u16* __restrict__ W,
    const float* __restrict__ bias,
    const u16* __restrict__ resb, int ldrb,
    float* __restrict__ Yf, int ldyf,
    u16* __restrict__ Yb, int ldyb,
    int K)
{
  __shared__ u16 As[64 * 32];
  __shared__ u16 Bs[64 * 32];
  const int t = threadIdx.x;
  const int m0 = blockIdx.y * 64, n0 = blockIdx.x * 64;
  const int r8 = t >> 2, c8 = (t & 3) * 8;
  const int lane = t & 63, w = t >> 6;
  const int cl = lane & 15, quad = lane >> 4;
  const int wm = (w >> 1) * 32, wn = (w & 1) * 32;

  f32x4 acc[2][2];
#pragma unroll
  for (int i = 0; i < 2; ++i)
#pragma unroll
    for (int j = 0; j < 2; ++j) acc[i][j] = (f32x4){0.f, 0.f, 0.f, 0.f};

  for (int k0 = 0; k0 < K; k0 += 32) {
    const u16* ag = A + (size_t)(m0 + r8) * lda + k0 + c8;
    const u16* bg = W + (size_t)(n0 + r8) * K + k0 + c8;
    __syncthreads();
    glds16(ag, &As[t * 8]);
    glds16(bg, &Bs[t * 8]);
    __syncthreads();

    short8 af[2], bfr[2];
#pragma unroll
    for (int i = 0; i < 2; ++i)
      af[i] = *(const short8*)&As[(wm + i * 16 + cl) * 32 + quad * 8];
#pragma unroll
    for (int j = 0; j < 2; ++j)
      bfr[j] = *(const short8*)&Bs[(wn + j * 16 + cl) * 32 + quad * 8];
#pragma unroll
    for (int mt = 0; mt < 2; ++mt)
#pragma unroll
      for (int nt = 0; nt < 2; ++nt)
        acc[mt][nt] = __builtin_amdgcn_mfma_f32_16x16x32_bf16(
            af[mt], bfr[nt], acc[mt][nt], 0, 0, 0);
  }

#pragma unroll
  for (int mt = 0; mt < 2; ++mt)
#pragma unroll
    for (int nt = 0; nt < 2; ++nt) {
      const int colg = n0 + wn + nt * 16 + cl;
      const float bs = bias[colg];
#pragma unroll
      for (int r = 0; r < 4; ++r) {
        const int rowg = m0 + wm + mt * 16 + quad * 4 + r;
        float v = acc[mt][nt][r] + bs;
        if (resb) v += bf2f(resb[(size_t)rowg * ldrb + colg]);
        if (Yf) Yf[(size_t)rowg * ldyf + colg] = v;
        if (Yb) Yb[(size_t)rowg * ldyb + colg] = f2bf(v);
      }
    }
}

// ---------------------------------------------------------------------------
// Weight fusion: W1f[n][k] = k<256 ? W1[n][k] : sum_m W1[n][256+m]*Wo[m][k-256]
// b1f[n] = b1[n] + sum_m W1[n][256+m]*bo[m].  All fp32 math, bf16 output.
// ---------------------------------------------------------------------------
__global__ __launch_bounds__(256) void wfuse_kernel(
    const float* __restrict__ W1, const float* __restrict__ Wo,
    const float* __restrict__ b1, const float* __restrict__ bo,
    const float* __restrict__ cW1, const float* __restrict__ cWo,
    const float* __restrict__ cb1, const float* __restrict__ cbo,
    u16* __restrict__ W1f, u16* __restrict__ cW1f,
    float* __restrict__ b1f, float* __restrict__ cb1f)
{
  const int n = blockIdx.x, sel = blockIdx.y;
  const float* Ws = sel ? cW1 : W1;
  const float* Wos = sel ? cWo : Wo;
  u16* out = sel ? cW1f : W1f;
  __shared__ float rowh[256];
  const int t = threadIdx.x;
  rowh[t] = Ws[(size_t)n * 512 + 256 + t];
  out[(size_t)n * 512 + t] = f2bf(Ws[(size_t)n * 512 + t]);
  __syncthreads();
  float acc = 0.f;
  for (int m = 0; m < 256; ++m) acc += rowh[m] * Wos[(size_t)m * 256 + t];
  out[(size_t)n * 512 + 256 + t] = f2bf(acc);
  if (t == 0) {
    const float* bos = sel ? cbo : bo;
    const float* b1s = sel ? cb1 : b1;
    float a = b1s[n];
    for (int m = 0; m < 256; ++m) a += rowh[m] * bos[m];
    (sel ? cb1f : b1f)[n] = a;
  }
}

// ---------------------------------------------------------------------------
// RoPE batched. qkv (M2,768) -> Qu (scaled 0.125*log2e), Ku, Vu bf16 (M2,256).
// ---------------------------------------------------------------------------
__global__ __launch_bounds__(256) void rope_repack_kernel(
    const u16* __restrict__ qkv, const float* __restrict__ enc0,
    const float* __restrict__ enc1,
    u16* __restrict__ Q, u16* __restrict__ K, u16* __restrict__ V)
{
  const int idx = blockIdx.x * blockDim.x + threadIdx.x;  // < M2*4*32
  const int i = idx & 31;
  const int h = (idx >> 5) & 3;
  const int m = idx >> 7;
  const int half = m >> 13;
  const int lm = m & (MROWS - 1);
  const float* enc = half ? enc1 : enc0;
  const u16* src = qkv + (size_t)m * 768 + h * 192 + i * 6;
  const unsigned a0 = *(const unsigned*)(src);
  const unsigned a1 = *(const unsigned*)(src + 2);
  const unsigned a2 = *(const unsigned*)(src + 4);
  const float q0 = bf2f((u16)a0), k0 = bf2f((u16)(a0 >> 16));
  const float v0 = bf2f((u16)a1), q1 = bf2f((u16)(a1 >> 16));
  const float k1 = bf2f((u16)a2), v1 = bf2f((u16)(a2 >> 16));
  const float c = enc[(size_t)lm * 64 + 2 * i];
  const float s = enc[(size_t)MROWS * 64 + (size_t)lm * 64 + 2 * i];
  const float QSC = 0.18033688011112042f;   // 0.125 * log2(e) -> exp2 softmax
  const size_t o = (size_t)m * 256 + h * 64 + 2 * i;
  *(unsigned*)(Q + o) = (unsigned)f2bf((q0 * c - q1 * s) * QSC) |
                        ((unsigned)f2bf((q1 * c + q0 * s) * QSC) << 16);
  *(unsigned*)(K + o) = (unsigned)f2bf(k0 * c - k1 * s) |
                        ((unsigned)f2bf(k1 * c + k0 * s) << 16);
  *(unsigned*)(V + o) = (unsigned)f2bf(v0) | ((unsigned)f2bf(v1) << 16);
}

// bf16 unheads (M2,256) -> bf16 transposed head-major (8,H,64,2048)
__global__ __launch_bounds__(256) void transpose_v_kernel(
    const u16* __restrict__ in, u16* __restrict__ out)
{
  __shared__ u16 Tl[64][72];
  const int bz = blockIdx.z, h = blockIdx.y;
  const int n0 = blockIdx.x * 64;
  const int t = threadIdx.x;
  {
    const int row = t >> 2, c16 = (t & 3) * 16;
    const u16* src = in + (size_t)(bz * NTOK + n0 + row) * 256 + h * 64 + c16;
    *(uint4*)&Tl[row][c16] = *(const uint4*)src;
    *(uint4*)&Tl[row][c16 + 8] = *(const uint4*)(src + 8);
  }
  __syncthreads();
  const int d = t >> 2, qr = t & 3;
  union { u16 u[16]; uint4 v[2]; } pk;
#pragma unroll
  for (int j = 0; j < 16; ++j) pk.u[j] = Tl[qr * 16 + j][d];
  u16* dst = out + ((size_t)((bz * NHEAD + h) * 64 + d)) * NTOK + n0 + qr * 16;
  *(uint4*)dst = pk.v[0];
  *(uint4*)(dst + 8) = pk.v[1];
}

// ---------------------------------------------------------------------------
// MFMA flash attention (S^T form, exp2 softmax, LDS-staged K/V with register
// prefetch — the measured-best r5 structure), 128-q blocks, 32 q/wave, plus:
//   - wave-uniform running max (6 shfls/tile, O-rescale skipped unless the
//     max moved — wave-uniform branch, no divergence)
//   - raw v_exp_f32 via __builtin_amdgcn_exp2f
// grid (16, 32, 2), block 256 = 4 waves. LDS 36.9 KB -> 4 blocks/CU.
// ---------------------------------------------------------------------------
__global__ __launch_bounds__(256, 4) void attn3_kernel(
    const u16* __restrict__ Qb, const u16* __restrict__ Kb,
    const u16* __restrict__ Vtb,
    u16* __restrict__ Po, float* __restrict__ Pm, float* __restrict__ Pl,
    int cross)
{
  __shared__ u16 Ks[64 * 72];
  __shared__ u16 Vs[64 * 72];
  __shared__ u16 QPs[128 * 72];  // Q tile at start, then per-wave P region
  const int y = blockIdx.y, z = blockIdx.z;
  const int h2 = y >> 4, b = (y >> 2) & 3, h = y & 3;
  const int kh = cross ? (1 - h2) : h2;
  const int qrowbase = (h2 * 4 + b) * NTOK;
  const int krowbase = (kh * 4 + b) * NTOK + z * 1024;
  const int vz = kh * 4 + b;
  const int n0 = blockIdx.x * 128;
  const int t = threadIdx.x, lane = t & 63, w = t >> 6;
  const int cl = lane & 15, quad = lane >> 4;

  // stage Q tile (128 x 64 bf16) once
  {
    const int row = t >> 1, c32 = (t & 1) * 32;
    const u16* src = Qb + (size_t)(qrowbase + n0 + row) * 256 + h * 64 + c32;
    uint4 v0 = *(const uint4*)src;
    uint4 v1 = *(const uint4*)(src + 8);
    uint4 v2 = *(const uint4*)(src + 16);
    uint4 v3 = *(const uint4*)(src + 24);
    u16* d = &QPs[row * 72 + c32];
    *(uint4*)d = v0; *(uint4*)(d + 8) = v1;
    *(uint4*)(d + 16) = v2; *(uint4*)(d + 24) = v3;
  }
  __syncthreads();
  const int q0 = w * 32;
  short8 bq[2][2];
#pragma unroll
  for (int c = 0; c < 2; ++c) {
    bq[c][0] = *(const short8*)&QPs[(q0 + c * 16 + cl) * 72 + quad * 8];
    bq[c][1] = *(const short8*)&QPs[(q0 + c * 16 + cl) * 72 + quad * 8 + 32];
  }

  float m_r = -1e30f;            // wave-uniform running max
  float l_r[2] = {0.f, 0.f};
  f32x4 o[2][4];
#pragma unroll
  for (int c = 0; c < 2; ++c)
#pragma unroll
    for (int i = 0; i < 4; ++i) o[c][i] = (f32x4){0.f, 0.f, 0.f, 0.f};

  const int srow = t >> 2, sc16 = (t & 3) * 16;
  const u16* Kg = Kb + (size_t)(krowbase + srow) * 256 + h * 64 + sc16;
  const u16* Vg = Vtb + ((size_t)(vz * NHEAD + h) * 64 + srow) * NTOK + z * 1024 + sc16;
  uint4 ka0 = *(const uint4*)Kg, ka1 = *(const uint4*)(Kg + 8);
  uint4 va0 = *(const uint4*)Vg, va1 = *(const uint4*)(Vg + 8);

  for (int tile = 0; tile < 16; ++tile) {
    __syncthreads();
    *(uint4*)&Ks[srow * 72 + sc16] = ka0;
    *(uint4*)&Ks[srow * 72 + sc16 + 8] = ka1;
    *(uint4*)&Vs[srow * 72 + sc16] = va0;
    *(uint4*)&Vs[srow * 72 + sc16 + 8] = va1;
    __syncthreads();
    if (tile < 15) {
      Kg += 64 * 256; Vg += 64;
      ka0 = *(const uint4*)Kg; ka1 = *(const uint4*)(Kg + 8);
      va0 = *(const uint4*)Vg; va1 = *(const uint4*)(Vg + 8);
    }

    // S^T strip: 64 keys x 32 q; K fragments shared by both q-columns
    f32x4 sf[2][4];
#pragma unroll
    for (int kb = 0; kb < 4; ++kb) {
      short8 ak0 = *(const short8*)&Ks[(kb * 16 + cl) * 72 + quad * 8];
      short8 ak1 = *(const short8*)&Ks[(kb * 16 + cl) * 72 + quad * 8 + 32];
#pragma unroll
      for (int c = 0; c < 2; ++c) {
        f32x4 acc = (f32x4){0.f, 0.f, 0.f, 0.f};
        acc = __builtin_amdgcn_mfma_f32_16x16x32_bf16(ak0, bq[c][0], acc, 0, 0, 0);
        acc = __builtin_amdgcn_mfma_f32_16x16x32_bf16(ak1, bq[c][1], acc, 0, 0, 0);
        sf[c][kb] = acc;
      }
    }

    // wave-uniform max over all 32 scores x 64 lanes
    float mx = sf[0][0][0];
#pragma unroll
    for (int c = 0; c < 2; ++c)
#pragma unroll
      for (int kb = 0; kb < 4; ++kb)
#pragma unroll
        for (int r = 0; r < 4; ++r) mx = fmaxf(mx, sf[c][kb][r]);
    mx = fmaxf(mx, __shfl_xor(mx, 1));
    mx = fmaxf(mx, __shfl_xor(mx, 2));
    mx = fmaxf(mx, __shfl_xor(mx, 4));
    mx = fmaxf(mx, __shfl_xor(mx, 8));
    mx = fmaxf(mx, __shfl_xor(mx, 16));
    mx = fmaxf(mx, __shfl_xor(mx, 32));
    const bool newmax = mx > m_r;
    const float mn = newmax ? mx : m_r;
    const float alpha = EXP2(m_r - mn);
    m_r = mn;

#pragma unroll
    for (int c = 0; c < 2; ++c) {
      float rs = 0.f;
#pragma unroll
      for (int kb = 0; kb < 4; ++kb)
#pragma unroll
        for (int r = 0; r < 4; ++r) {
          const float p = EXP2(sf[c][kb][r] - mn);
          sf[c][kb][r] = p; rs += p;
        }
      rs += __shfl_xor(rs, 16);
      rs += __shfl_xor(rs, 32);
      l_r[c] = l_r[c] * alpha + rs;
      // P rows (q-major) into wave-private LDS region
#pragma unroll
      for (int kb = 0; kb < 4; ++kb) {
        unsigned d0 = __builtin_amdgcn_perm(__float_as_uint(sf[c][kb][1]),
                                            __float_as_uint(sf[c][kb][0]), 0x07060302u);
        unsigned d1 = __builtin_amdgcn_perm(__float_as_uint(sf[c][kb][3]),
                                            __float_as_uint(sf[c][kb][2]), 0x07060302u);
        uint2 pk; pk.x = d0; pk.y = d1;
        *(uint2*)&QPs[(q0 + c * 16 + cl) * 72 + kb * 16 + quad * 4] = pk;
      }
    }
    if (newmax) {   // wave-uniform branch: rescale only when max moved
#pragma unroll
      for (int c = 0; c < 2; ++c)
#pragma unroll
        for (int db = 0; db < 4; ++db) o[c][db] *= alpha;
    }

    // O^T += V^T P^T; V fragments shared by both q-columns
    short8 bp[2][2];
#pragma unroll
    for (int c = 0; c < 2; ++c) {
      bp[c][0] = *(const short8*)&QPs[(q0 + c * 16 + cl) * 72 + quad * 8];
      bp[c][1] = *(const short8*)&QPs[(q0 + c * 16 + cl) * 72 + quad * 8 + 32];
    }
#pragma unroll
    for (int db = 0; db < 4; ++db) {
      short8 av0 = *(const short8*)&Vs[(db * 16 + cl) * 72 + quad * 8];
      short8 av1 = *(const short8*)&Vs[(db * 16 + cl) * 72 + quad * 8 + 32];
#pragma unroll
      for (int c = 0; c < 2; ++c) {
        o[c][db] = __builtin_amdgcn_mfma_f32_16x16x32_bf16(av0, bp[c][0], o[c][db], 0, 0, 0);
        o[c][db] = __builtin_amdgcn_mfma_f32_16x16x32_bf16(av1, bp[c][1], o[c][db], 0, 0, 0);
      }
    }
  }

  // store partials
#pragma unroll
  for (int c = 0; c < 2; ++c) {
    const int rp = z * 65536 + y * 2048 + n0 + q0 + c * 16 + cl;
#pragma unroll
    for (int db = 0; db < 4; ++db) {
      ushort4 st;
      st.x = f2bf(o[c][db][0]); st.y = f2bf(o[c][db][1]);
      st.z = f2bf(o[c][db][2]); st.w = f2bf(o[c][db][3]);
      *(ushort4*)(Po + (size_t)rp * 64 + db * 16 + quad * 4) = st;
    }
    if (quad == 0) { Pm[rp] = m_r; Pl[rp] = l_r[c]; }
  }
}

// combine the 2 K-split partials (exp2 domain) -> bf16 unheads output
__global__ __launch_bounds__(256) void attn_combine_kernel(
    const u16* __restrict__ Po, const float* __restrict__ Pm,
    const float* __restrict__ Pl, u16* __restrict__ Ou)
{
  const int rowi = blockIdx.x * 4 + (threadIdx.x >> 6);
  const int lane = threadIdx.x & 63;
  const float m0 = Pm[rowi], m1 = Pm[65536 + rowi];
  const float l0 = Pl[rowi], l1 = Pl[65536 + rowi];
  const float M = fmaxf(m0, m1);
  const float e0 = EXP2(m0 - M), e1 = EXP2(m1 - M);
  const float inv = 1.f / (e0 * l0 + e1 * l1);
  const float o0 = bf2f(Po[(size_t)rowi * 64 + lane]);
  const float o1 = bf2f(Po[(size_t)65536 * 64 + (size_t)rowi * 64 + lane]);
  const float val = (e0 * o0 + e1 * o1) * inv;
  const int y = rowi >> 11, q = rowi & 2047;
  const int bz = y >> 2, h = y & 3;
  Ou[(size_t)(bz * NTOK + q) * 256 + h * 64 + lane] = f2bf(val);
}

// ---------------------------------------------------------------------------
// LayerNorm + exact GELU, bf16 in (M2,512) -> bf16 out
// ---------------------------------------------------------------------------
__global__ __launch_bounds__(256) void ln_gelu_kernel(
    const u16* __restrict__ Hm, const float* __restrict__ g,
    const float* __restrict__ be, u16* __restrict__ out)
{
  const int rowi = blockIdx.x * 4 + (threadIdx.x >> 6);
  const int lane = threadIdx.x & 63;
  const u16* row = Hm + (size_t)rowi * 512 + lane * 8;
  u16* orow = out + (size_t)rowi * 512 + lane * 8;
  uint4 raw = *(const uint4*)row;
  float x[8];
  const unsigned* rw = (const unsigned*)&raw;
#pragma unroll
  for (int i = 0; i < 4; ++i) {
    x[2 * i]     = bf2f((u16)rw[i]);
    x[2 * i + 1] = bf2f((u16)(rw[i] >> 16));
  }
  float s = 0.f;
#pragma unroll
  for (int i = 0; i < 8; ++i) s += x[i];
#pragma unroll
  for (int off = 32; off; off >>= 1) s += __shfl_xor(s, off);
  const float mean = s * (1.f / 512.f);
  float s2 = 0.f;
#pragma unroll
  for (int i = 0; i < 8; ++i) { const float d = x[i] - mean; s2 += d * d; }
#pragma unroll
  for (int off = 32; off; off >>= 1) s2 += __shfl_xor(s2, off);
  const float rstd = rsqrtf(s2 * (1.f / 512.f) + 1e-5f);
  unsigned ov[4];
#pragma unroll
  for (int i = 0; i < 4; ++i) {
    const int c = lane * 8 + 2 * i;
    const float y0 = (x[2 * i] - mean) * rstd * g[c] + be[c];
    const float y1 = (x[2 * i + 1] - mean) * rstd * g[c + 1] + be[c + 1];
    const float g0 = 0.5f * y0 * (1.f + erff(y0 * 0.70710678118654752f));
    const float g1 = 0.5f * y1 * (1.f + erff(y1 * 0.70710678118654752f));
    ov[i] = (unsigned)f2bf(g0) | ((unsigned)f2bf(g1) << 16);
  }
  *(uint4*)orow = *(uint4*)ov;
}

// ---------------------------------------------------------------------------
// pack everything fp32 -> bf16: 5 weight mats (589824 elems) + 2 descs.
// ---------------------------------------------------------------------------
__global__ __launch_bounds__(256) void pack_all_kernel(
    const float* w0, const float* w1, const float* w2, const float* w3,
    const float* w4, const float* d0, const float* d1,
    u16* __restrict__ wb, u16* __restrict__ descb)
{
  const size_t idx4 = ((size_t)blockIdx.x * 256 + threadIdx.x) * 4;
  const float* src; u16* dst; size_t off;
  if (idx4 < 589824) {
    off = idx4; dst = wb + idx4;
    if      (idx4 < 196608) { src = w0; }
    else if (idx4 < 327680) { src = w1; off -= 196608; }
    else if (idx4 < 393216) { src = w2; off -= 327680; }
    else if (idx4 < 458752) { src = w3; off -= 393216; }
    else                    { src = w4; off -= 458752; }
  } else {
    size_t o = idx4 - 589824;
    dst = descb + o;
    if (o < NMu) { src = d0; off = o; }
    else         { src = d1; off = o - NMu; }
  }
  float4 v = *(const float4*)(src + off);
  ushort4 ov;
  ov.x = f2bf(v.x); ov.y = f2bf(v.y); ov.z = f2bf(v.z); ov.w = f2bf(v.w);
  *(ushort4*)dst = ov;
}

// ---------------------------------------------------------------------------
extern "C" void kernel_launch(void* const* d_in, const int* in_sizes, int n_in,
                              void* d_out, int out_size, void* d_ws, size_t ws_size,
                              hipStream_t stream) {
  const float* desc0  = (const float*)d_in[0];
  const float* desc1  = (const float*)d_in[1];
  const float* enc0   = (const float*)d_in[2];
  const float* enc1   = (const float*)d_in[3];
  const float* s_Wqkv = (const float*)d_in[4];
  const float* s_bqkv = (const float*)d_in[5];
  const float* s_Wout = (const float*)d_in[6];
  const float* s_bout = (const float*)d_in[7];
  const float* s_W1   = (const float*)d_in[8];
  const float* s_b1   = (const float*)d_in[9];
  const float* s_g    = (const float*)d_in[10];
  const float* s_be   = (const float*)d_in[11];
  const float* s_W2   = (const float*)d_in[12];
  const float* s_b2   = (const float*)d_in[13];
  const float* c_Wqk  = (const float*)d_in[14];
  const float* c_bqk  = (const float*)d_in[15];
  const float* c_Wv   = (const float*)d_in[16];
  const float* c_bv   = (const float*)d_in[17];
  const float* c_Wo   = (const float*)d_in[18];
  const float* c_bo   = (const float*)d_in[19];
  const float* c_W1   = (const float*)d_in[20];
  const float* c_b1   = (const float*)d_in[21];
  const float* c_g    = (const float*)d_in[22];
  const float* c_be   = (const float*)d_in[23];
  const float* c_W2   = (const float*)d_in[24];
  const float* c_b2   = (const float*)d_in[25];

  u16* U = (u16*)d_ws;
  u16* descb = U + 0 * NMu;             // [all]
  u16* qkvb  = U + 2 * NMu;             // 6u, phase A only
  u16* ctxb  = U + 2 * NMu;             // 2u, combine out (self B / cross E)
  u16* Qu    = U + 8 * NMu;             // self Q / cross qkb
  u16* Ku    = U + 10 * NMu;            // self K / cross vb
  u16* Vu    = U + 12 * NMu;            // self V staging
  u16* Vt    = U + 14 * NMu;            // transposed V
  u16* hbufb = U + 12 * NMu;            // 4u ffn hidden (after attn)
  u16* Po    = U + 16 * NMu;            // 4u attn partials
  u16* hb2   = U + 16 * NMu;            // 4u ln out (after combine)
  float* Pm  = (float*)(U + 20 * NMu);
  float* Pl  = Pm + 2 * 65536;
  float* b1f = Pl + 2 * 65536;          // 512 fp32
  float* cb1f = b1f + 512;
  u16* s_b   = U + 21 * NMu;            // self outputs
  u16* wb    = U + 23 * NMu;

  u16* Wqkvb = wb;                      // 196608
  u16* W2b   = wb + 196608;             // 131072
  u16* cQKVb = wb + 327680;             // cWqk(65536) || cWv(65536)
  u16* cW2b  = wb + 458752;             // 131072
  u16* W1f   = wb + 589824;             // 262144 (fused self FFN1 weight)
  u16* cW1f  = wb + 851968;             // 262144

  float* outf = (float*)d_out;

  const dim3 attn_grid(NTOK / 128, 32, 2);
  const dim3 tv_grid(NTOK / 64, NHEAD, 8);
  const int rope_blocks = (M2 * 128) / 256;
  const int lng_blocks  = M2 / 4;
  const int comb_blocks = 65536 / 4;
  const float csc = 0.42466090014400953f;  // 8^-0.5 * sqrt(log2 e)

  // 1. pack weights + descs
  hipLaunchKernelGGL(pack_all_kernel, dim3(4672), dim3(256), 0, stream,
                     s_Wqkv, s_W2, c_Wqk, c_Wv, c_W2, desc0, desc1, wb, descb);
  // 2. fold Wout->W1, cWo->cW1 (+bias folds)
  hipLaunchKernelGGL(wfuse_kernel, dim3(512, 2), dim3(256), 0, stream,
                     s_W1, s_Wout, s_b1, s_bout, c_W1, c_Wo, c_b1, c_bo,
                     W1f, cW1f, b1f, cb1f);

  // ---------------- self blocks (batched) ----------------
  // 3. qkv GEMM
  hipLaunchKernelGGL(gemm_bf16_kernel, dim3(6, 128), dim3(256), 0, stream,
                     descb, 256, (const u16*)nullptr, 0, 1 << 30, Wqkvb,
                     s_bqkv, (const float*)nullptr, 1 << 30, 1.f, 1.f,
                     qkvb, 768, (u16*)nullptr, 0, 256);
  // 4. rope
  hipLaunchKernelGGL(rope_repack_kernel, dim3(rope_blocks), dim3(256), 0, stream,
                     qkvb, enc0, enc1, Qu, Ku, Vu);
  // 5. transpose V
  hipLaunchKernelGGL(transpose_v_kernel, tv_grid, dim3(256), 0, stream, Vu, Vt);
  // 6/7. attention + combine
  hipLaunchKernelGGL(attn3_kernel, attn_grid, dim3(256), 0, stream,
                     Qu, Ku, Vt, Po, Pm, Pl, 0);
  hipLaunchKernelGGL(attn_combine_kernel, dim3(comb_blocks), dim3(256), 0, stream,
                     Po, Pm, Pl, ctxb);
  // 8. FFN1 (fused Wout): A=[descb | ctxb] @ W1f^T + b1f
  hipLaunchKernelGGL(gemm_bf16_kernel, dim3(4, 128), dim3(256), 0, stream,
                     descb, 256, ctxb, 256, 256, W1f,
                     b1f, (const float*)nullptr, 1 << 30, 1.f, 1.f,
                     hbufb, 512, (u16*)nullptr, 0, 512);
  // 9. LN + GELU
  hipLaunchKernelGGL(ln_gelu_kernel, dim3(lng_blocks), dim3(256), 0, stream,
                     hbufb, s_g, s_be, hb2);
  // 10. W2 + residual
  hipLaunchKernelGGL(gemm64_kernel, dim3(4, 256), dim3(256), 0, stream,
                     hb2, 512, W2b, s_b2, descb, 256,
                     (float*)nullptr, 0, s_b, 256, 512);

  // ---------------- cross block (batched) ----------------
  u16* qkb = Qu;
  u16* vb  = Ku;
  // 11. fused qk|v projection (per-half bias/scale/output)
  hipLaunchKernelGGL(gemm_bf16_kernel, dim3(4, 128), dim3(256), 0, stream,
                     s_b, 256, (const u16*)nullptr, 0, 1 << 30, cQKVb,
                     c_bqk, c_bv, 256, csc, 1.f,
                     qkb, 256, vb, 256, 256);
  // 12. transpose V
  hipLaunchKernelGGL(transpose_v_kernel, tv_grid, dim3(256), 0, stream, vb, Vt);
  // 13/14. attention + combine
  hipLaunchKernelGGL(attn3_kernel, attn_grid, dim3(256), 0, stream,
                     qkb, qkb, Vt, Po, Pm, Pl, 1);
  hipLaunchKernelGGL(attn_combine_kernel, dim3(comb_blocks), dim3(256), 0, stream,
                     Po, Pm, Pl, ctxb);
  // 15. FFN1 (fused cWo)
  hipLaunchKernelGGL(gemm_bf16_kernel, dim3(4, 128), dim3(256), 0, stream,
                     s_b, 256, ctxb, 256, 256, cW1f,
                     cb1f, (const float*)nullptr, 1 << 30, 1.f, 1.f,
                     hbufb, 512, (u16*)nullptr, 0, 512);
  // 16. LN + GELU
  hipLaunchKernelGGL(ln_gelu_kernel, dim3(lng_blocks), dim3(256), 0, stream,
                     hbufb, c_g, c_be, hb2);
  // 17. W2 + residual -> fp32 output
  hipLaunchKernelGGL(gemm64_kernel, dim3(4, 256), dim3(256), 0, stream,
                     hb2, 512, cW2b, c_b2, s_b, 256,
                     outf, 256, (u16*)nullptr, 0, 512);
}

// Round 9
// 395.115 us; speedup vs baseline: 1.3914x; 1.0906x over previous
//
#include <hip/hip_runtime.h>
#include <cstddef>

#define NTOK 2048
#define BDIM 4
#define DIM 256
#define NHEAD 4
#define MROWS 8192
#define M2 16384                        // both descriptors batched
#define NMu ((size_t)MROWS * DIM)       // 2,097,152 elems (bf16 unit = 4 MB)

typedef unsigned short u16;
typedef __attribute__((ext_vector_type(8))) short short8;
typedef __attribute__((ext_vector_type(4))) float f32x4;

#if __has_builtin(__builtin_amdgcn_exp2f)
#define EXP2(x) __builtin_amdgcn_exp2f(x)
#else
#define EXP2(x) exp2f(x)
#endif

__device__ __forceinline__ u16 f2bf(float x) {
  union { float f; unsigned u; } c; c.f = x;
  unsigned r = c.u + 0x7FFFu + ((c.u >> 16) & 1u);
  return (u16)(r >> 16);
}
__device__ __forceinline__ float bf2f(u16 u) {
  union { unsigned u; float f; } c; c.u = ((unsigned)u) << 16;
  return c.f;
}

__device__ __forceinline__ void glds16(const void* g, void* l) {
  __builtin_amdgcn_global_load_lds(
      (const __attribute__((address_space(1))) unsigned int*)g,
      (__attribute__((address_space(3))) unsigned int*)l, 16, 0, 0);
}

// ---------------------------------------------------------------------------
// bf16 MFMA GEMM, 128x128 tile, BK=64 as two stacked BK=32 LDS panels
// (keeps glds16 lane-contiguity AND conflict-free pitch-32 fragment reads).
// Y = (A @ W^T + bias)*oscale; A split at kSplit; N split at nsplit.
// ---------------------------------------------------------------------------
__global__ __launch_bounds__(256) void gemm_bf16_kernel(
    const u16* __restrict__ A, int lda,
    const u16* __restrict__ A2, int lda2, int kSplit,
    const u16* __restrict__ W,
    const float* __restrict__ bias0, const float* __restrict__ bias1,
    int nsplit, float os0, float os1,
    u16* __restrict__ Yb0, int ldy0,
    u16* __restrict__ Yb1, int ldy1,
    int K)
{
  __shared__ u16 As[2 * 4096];   // [kh][row][32]
  __shared__ u16 Bs[2 * 4096];
  const int t = threadIdx.x;
  const int m0 = blockIdx.y * 128, n0 = blockIdx.x * 128;
  const int r4 = t >> 2, c8 = (t & 3) * 8;
  const int lane = t & 63, w = t >> 6;
  const int cl = lane & 15, quad = lane >> 4;
  const int wm = (w >> 1) * 64, wn = (w & 1) * 64;

  f32x4 acc[4][4];
#pragma unroll
  for (int i = 0; i < 4; ++i)
#pragma unroll
    for (int j = 0; j < 4; ++j) acc[i][j] = (f32x4){0.f, 0.f, 0.f, 0.f};

  for (int k0 = 0; k0 < K; k0 += 64) {
    const u16* Ab; int la; int kk;
    if (k0 < kSplit) { Ab = A; la = lda; kk = k0; }
    else             { Ab = A2; la = lda2; kk = k0 - kSplit; }
    const u16* ag = Ab + (size_t)(m0 + r4) * la + kk + c8;
    const u16* bg = W + (size_t)(n0 + r4) * K + k0 + c8;
    __syncthreads();
#pragma unroll
    for (int kh = 0; kh < 2; ++kh) {
      glds16(ag + kh * 32, &As[kh * 4096 + t * 8]);
      glds16(ag + (size_t)64 * la + kh * 32, &As[kh * 4096 + 2048 + t * 8]);
      glds16(bg + kh * 32, &Bs[kh * 4096 + t * 8]);
      glds16(bg + (size_t)64 * K + kh * 32, &Bs[kh * 4096 + 2048 + t * 8]);
    }
    __syncthreads();

#pragma unroll
    for (int kh = 0; kh < 2; ++kh) {
      short8 af[4], bfr[4];
#pragma unroll
      for (int i = 0; i < 4; ++i)
        af[i] = *(const short8*)&As[kh * 4096 + (wm + i * 16 + cl) * 32 + quad * 8];
#pragma unroll
      for (int i = 0; i < 4; ++i)
        bfr[i] = *(const short8*)&Bs[kh * 4096 + (wn + i * 16 + cl) * 32 + quad * 8];
#pragma unroll
      for (int mt = 0; mt < 4; ++mt)
#pragma unroll
        for (int nt = 0; nt < 4; ++nt)
          acc[mt][nt] = __builtin_amdgcn_mfma_f32_16x16x32_bf16(
              af[mt], bfr[nt], acc[mt][nt], 0, 0, 0);
    }
  }

#pragma unroll
  for (int mt = 0; mt < 4; ++mt)
#pragma unroll
    for (int nt = 0; nt < 4; ++nt) {
      const int colg = n0 + wn + nt * 16 + cl;
      const bool first = colg < nsplit;
      const int c2 = first ? colg : colg - nsplit;
      const float bs = first ? bias0[c2] : bias1[c2];
      const float os = first ? os0 : os1;
      u16* yb = first ? Yb0 : Yb1;
      const int ly = first ? ldy0 : ldy1;
#pragma unroll
      for (int r = 0; r < 4; ++r) {
        const int rowg = m0 + wm + mt * 16 + quad * 4 + r;
        yb[(size_t)rowg * ly + c2] = f2bf((acc[mt][nt][r] + bs) * os);
      }
    }
}

// ---------------------------------------------------------------------------
// bf16 MFMA GEMM, 64x64 tile, BK=64 (two BK=32 panels). N==256 GEMMs.
// ---------------------------------------------------------------------------
__global__ __launch_bounds__(256) void gemm64_kernel(
    const u16* __restrict__ A, int lda,
    const u16* __restrict__ W,
    const float* __restrict__ bias,
    const u16* __restrict__ resb, int ldrb,
    float* __restrict__ Yf, int ldyf,
    u16* __restrict__ Yb, int ldyb,
    int K)
{
  __shared__ u16 As[2 * 2048];
  __shared__ u16 Bs[2 * 2048];
  const int t = threadIdx.x;
  const int m0 = blockIdx.y * 64, n0 = blockIdx.x * 64;
  const int r8 = t >> 2, c8 = (t & 3) * 8;
  const int lane = t & 63, w = t >> 6;
  const int cl = lane & 15, quad = lane >> 4;
  const int wm = (w >> 1) * 32, wn = (w & 1) * 32;

  f32x4 acc[2][2];
#pragma unroll
  for (int i = 0; i < 2; ++i)
#pragma unroll
    for (int j = 0; j < 2; ++j) acc[i][j] = (f32x4){0.f, 0.f, 0.f, 0.f};

  for (int k0 = 0; k0 < K; k0 += 64) {
    const u16* ag = A + (size_t)(m0 + r8) * lda + k0 + c8;
    const u16* bg = W + (size_t)(n0 + r8) * K + k0 + c8;
    __syncthreads();
#pragma unroll
    for (int kh = 0; kh < 2; ++kh) {
      glds16(ag + kh * 32, &As[kh * 2048 + t * 8]);
      glds16(bg + kh * 32, &Bs[kh * 2048 + t * 8]);
    }
    __syncthreads();

#pragma unroll
    for (int kh = 0; kh < 2; ++kh) {
      short8 af[2], bfr[2];
#pragma unroll
      for (int i = 0; i < 2; ++i)
        af[i] = *(const short8*)&As[kh * 2048 + (wm + i * 16 + cl) * 32 + quad * 8];
#pragma unroll
      for (int j = 0; j < 2; ++j)
        bfr[j] = *(const short8*)&Bs[kh * 2048 + (wn + j * 16 + cl) * 32 + quad * 8];
#pragma unroll
      for (int mt = 0; mt < 2; ++mt)
#pragma unroll
        for (int nt = 0; nt < 2; ++nt)
          acc[mt][nt] = __builtin_amdgcn_mfma_f32_16x16x32_bf16(
              af[mt], bfr[nt], acc[mt][nt], 0, 0, 0);
    }
  }

#pragma unroll
  for (int mt = 0; mt < 2; ++mt)
#pragma unroll
    for (int nt = 0; nt < 2; ++nt) {
      const int colg = n0 + wn + nt * 16 + cl;
      const float bs = bias[colg];
#pragma unroll
      for (int r = 0; r < 4; ++r) {
        const int rowg = m0 + wm + mt * 16 + quad * 4 + r;
        float v = acc[mt][nt][r] + bs;
        if (resb) v += bf2f(resb[(size_t)rowg * ldrb + colg]);
        if (Yf) Yf[(size_t)rowg * ldyf + colg] = v;
        if (Yb) Yb[(size_t)rowg * ldyb + colg] = f2bf(v);
      }
    }
}

// ---------------------------------------------------------------------------
// Weight fusion: W1f[n][k] = k<256 ? W1[n][k] : sum_m W1[n][256+m]*Wo[m][k-256]
// b1f[n] = b1[n] + sum_m W1[n][256+m]*bo[m].  All fp32 math, bf16 output.
// ---------------------------------------------------------------------------
__global__ __launch_bounds__(256) void wfuse_kernel(
    const float* __restrict__ W1, const float* __restrict__ Wo,
    const float* __restrict__ b1, const float* __restrict__ bo,
    const float* __restrict__ cW1, const float* __restrict__ cWo,
    const float* __restrict__ cb1, const float* __restrict__ cbo,
    u16* __restrict__ W1f, u16* __restrict__ cW1f,
    float* __restrict__ b1f, float* __restrict__ cb1f)
{
  const int n = blockIdx.x, sel = blockIdx.y;
  const float* Ws = sel ? cW1 : W1;
  const float* Wos = sel ? cWo : Wo;
  u16* out = sel ? cW1f : W1f;
  __shared__ float rowh[256];
  const int t = threadIdx.x;
  rowh[t] = Ws[(size_t)n * 512 + 256 + t];
  out[(size_t)n * 512 + t] = f2bf(Ws[(size_t)n * 512 + t]);
  __syncthreads();
  float acc = 0.f;
  for (int m = 0; m < 256; ++m) acc += rowh[m] * Wos[(size_t)m * 256 + t];
  out[(size_t)n * 512 + 256 + t] = f2bf(acc);
  if (t == 0) {
    const float* bos = sel ? cbo : bo;
    const float* b1s = sel ? cb1 : b1;
    float a = b1s[n];
    for (int m = 0; m < 256; ++m) a += rowh[m] * bos[m];
    (sel ? cb1f : b1f)[n] = a;
  }
}

// ---------------------------------------------------------------------------
// RoPE batched. qkv (M2,768) -> Qu (scaled 0.125*log2e), Ku, Vu bf16 (M2,256).
// ---------------------------------------------------------------------------
__global__ __launch_bounds__(256) void rope_repack_kernel(
    const u16* __restrict__ qkv, const float* __restrict__ enc0,
    const float* __restrict__ enc1,
    u16* __restrict__ Q, u16* __restrict__ K, u16* __restrict__ V)
{
  const int idx = blockIdx.x * blockDim.x + threadIdx.x;  // < M2*4*32
  const int i = idx & 31;
  const int h = (idx >> 5) & 3;
  const int m = idx >> 7;
  const int half = m >> 13;
  const int lm = m & (MROWS - 1);
  const float* enc = half ? enc1 : enc0;
  const u16* src = qkv + (size_t)m * 768 + h * 192 + i * 6;
  const unsigned a0 = *(const unsigned*)(src);
  const unsigned a1 = *(const unsigned*)(src + 2);
  const unsigned a2 = *(const unsigned*)(src + 4);
  const float q0 = bf2f((u16)a0), k0 = bf2f((u16)(a0 >> 16));
  const float v0 = bf2f((u16)a1), q1 = bf2f((u16)(a1 >> 16));
  const float k1 = bf2f((u16)a2), v1 = bf2f((u16)(a2 >> 16));
  const float c = enc[(size_t)lm * 64 + 2 * i];
  const float s = enc[(size_t)MROWS * 64 + (size_t)lm * 64 + 2 * i];
  const float QSC = 0.18033688011112042f;   // 0.125 * log2(e) -> exp2 softmax
  const size_t o = (size_t)m * 256 + h * 64 + 2 * i;
  *(unsigned*)(Q + o) = (unsigned)f2bf((q0 * c - q1 * s) * QSC) |
                        ((unsigned)f2bf((q1 * c + q0 * s) * QSC) << 16);
  *(unsigned*)(K + o) = (unsigned)f2bf(k0 * c - k1 * s) |
                        ((unsigned)f2bf(k1 * c + k0 * s) << 16);
  *(unsigned*)(V + o) = (unsigned)f2bf(v0) | ((unsigned)f2bf(v1) << 16);
}

// bf16 unheads (M2,256) -> bf16 transposed head-major (8,H,64,2048)
__global__ __launch_bounds__(256) void transpose_v_kernel(
    const u16* __restrict__ in, u16* __restrict__ out)
{
  __shared__ u16 Tl[64][72];
  const int bz = blockIdx.z, h = blockIdx.y;
  const int n0 = blockIdx.x * 64;
  const int t = threadIdx.x;
  {
    const int row = t >> 2, c16 = (t & 3) * 16;
    const u16* src = in + (size_t)(bz * NTOK + n0 + row) * 256 + h * 64 + c16;
    *(uint4*)&Tl[row][c16] = *(const uint4*)src;
    *(uint4*)&Tl[row][c16 + 8] = *(const uint4*)(src + 8);
  }
  __syncthreads();
  const int d = t >> 2, qr = t & 3;
  union { u16 u[16]; uint4 v[2]; } pk;
#pragma unroll
  for (int j = 0; j < 16; ++j) pk.u[j] = Tl[qr * 16 + j][d];
  u16* dst = out + ((size_t)((bz * NHEAD + h) * 64 + d)) * NTOK + n0 + qr * 16;
  *(uint4*)dst = pk.v[0];
  *(uint4*)(dst + 8) = pk.v[1];
}

// ---------------------------------------------------------------------------
// MFMA flash attention, MAX-FREE exp2 softmax (scores bounded ~|4|, fp32
// exp2 safe to ~120; softmax is shift-invariant so result is exact).
// S^T form, LDS-staged K/V + register prefetch, 128-q blocks, 32 q/wave.
// K-split partials combine exactly: O = (o0+o1)/(l0+l1).
// grid (16, 32, 2), block 256 = 4 waves. LDS 36.9 KB -> 4 blocks/CU.
// ---------------------------------------------------------------------------
__global__ __launch_bounds__(256, 4) void attn3_kernel(
    const u16* __restrict__ Qb, const u16* __restrict__ Kb,
    const u16* __restrict__ Vtb,
    u16* __restrict__ Po, float* __restrict__ Pl,
    int cross)
{
  __shared__ u16 Ks[64 * 72];
  __shared__ u16 Vs[64 * 72];
  __shared__ u16 QPs[128 * 72];  // Q tile at start, then per-wave P region
  const int y = blockIdx.y, z = blockIdx.z;
  const int h2 = y >> 4, b = (y >> 2) & 3, h = y & 3;
  const int kh = cross ? (1 - h2) : h2;
  const int qrowbase = (h2 * 4 + b) * NTOK;
  const int krowbase = (kh * 4 + b) * NTOK + z * 1024;
  const int vz = kh * 4 + b;
  const int n0 = blockIdx.x * 128;
  const int t = threadIdx.x, lane = t & 63, w = t >> 6;
  const int cl = lane & 15, quad = lane >> 4;

  // stage Q tile (128 x 64 bf16) once
  {
    const int row = t >> 1, c32 = (t & 1) * 32;
    const u16* src = Qb + (size_t)(qrowbase + n0 + row) * 256 + h * 64 + c32;
    uint4 v0 = *(const uint4*)src;
    uint4 v1 = *(const uint4*)(src + 8);
    uint4 v2 = *(const uint4*)(src + 16);
    uint4 v3 = *(const uint4*)(src + 24);
    u16* d = &QPs[row * 72 + c32];
    *(uint4*)d = v0; *(uint4*)(d + 8) = v1;
    *(uint4*)(d + 16) = v2; *(uint4*)(d + 24) = v3;
  }
  __syncthreads();
  const int q0 = w * 32;
  short8 bq[2][2];
#pragma unroll
  for (int c = 0; c < 2; ++c) {
    bq[c][0] = *(const short8*)&QPs[(q0 + c * 16 + cl) * 72 + quad * 8];
    bq[c][1] = *(const short8*)&QPs[(q0 + c * 16 + cl) * 72 + quad * 8 + 32];
  }

  float l_r[2] = {0.f, 0.f};
  f32x4 o[2][4];
#pragma unroll
  for (int c = 0; c < 2; ++c)
#pragma unroll
    for (int i = 0; i < 4; ++i) o[c][i] = (f32x4){0.f, 0.f, 0.f, 0.f};

  const int srow = t >> 2, sc16 = (t & 3) * 16;
  const u16* Kg = Kb + (size_t)(krowbase + srow) * 256 + h * 64 + sc16;
  const u16* Vg = Vtb + ((size_t)(vz * NHEAD + h) * 64 + srow) * NTOK + z * 1024 + sc16;
  uint4 ka0 = *(const uint4*)Kg, ka1 = *(const uint4*)(Kg + 8);
  uint4 va0 = *(const uint4*)Vg, va1 = *(const uint4*)(Vg + 8);

  for (int tile = 0; tile < 16; ++tile) {
    __syncthreads();
    *(uint4*)&Ks[srow * 72 + sc16] = ka0;
    *(uint4*)&Ks[srow * 72 + sc16 + 8] = ka1;
    *(uint4*)&Vs[srow * 72 + sc16] = va0;
    *(uint4*)&Vs[srow * 72 + sc16 + 8] = va1;
    __syncthreads();
    if (tile < 15) {
      Kg += 64 * 256; Vg += 64;
      ka0 = *(const uint4*)Kg; ka1 = *(const uint4*)(Kg + 8);
      va0 = *(const uint4*)Vg; va1 = *(const uint4*)(Vg + 8);
    }

    // S^T strip: 64 keys x 32 q; K fragments shared by both q-columns
    f32x4 sf[2][4];
#pragma unroll
    for (int kb = 0; kb < 4; ++kb) {
      short8 ak0 = *(const short8*)&Ks[(kb * 16 + cl) * 72 + quad * 8];
      short8 ak1 = *(const short8*)&Ks[(kb * 16 + cl) * 72 + quad * 8 + 32];
#pragma unroll
      for (int c = 0; c < 2; ++c) {
        f32x4 acc = (f32x4){0.f, 0.f, 0.f, 0.f};
        acc = __builtin_amdgcn_mfma_f32_16x16x32_bf16(ak0, bq[c][0], acc, 0, 0, 0);
        acc = __builtin_amdgcn_mfma_f32_16x16x32_bf16(ak1, bq[c][1], acc, 0, 0, 0);
        sf[c][kb] = acc;
      }
    }

    // p = exp2(s) directly (no max), row sums, P to wave-private LDS rows
#pragma unroll
    for (int c = 0; c < 2; ++c) {
      float rs = 0.f;
#pragma unroll
      for (int kb = 0; kb < 4; ++kb)
#pragma unroll
        for (int r = 0; r < 4; ++r) {
          const float p = EXP2(sf[c][kb][r]);
          sf[c][kb][r] = p; rs += p;
        }
      rs += __shfl_xor(rs, 16);
      rs += __shfl_xor(rs, 32);
      l_r[c] += rs;
#pragma unroll
      for (int kb = 0; kb < 4; ++kb) {
        unsigned d0 = __builtin_amdgcn_perm(__float_as_uint(sf[c][kb][1]),
                                            __float_as_uint(sf[c][kb][0]), 0x07060302u);
        unsigned d1 = __builtin_amdgcn_perm(__float_as_uint(sf[c][kb][3]),
                                            __float_as_uint(sf[c][kb][2]), 0x07060302u);
        uint2 pk; pk.x = d0; pk.y = d1;
        *(uint2*)&QPs[(q0 + c * 16 + cl) * 72 + kb * 16 + quad * 4] = pk;
      }
    }

    // O^T += V^T P^T; V fragments shared by both q-columns
    short8 bp[2][2];
#pragma unroll
    for (int c = 0; c < 2; ++c) {
      bp[c][0] = *(const short8*)&QPs[(q0 + c * 16 + cl) * 72 + quad * 8];
      bp[c][1] = *(const short8*)&QPs[(q0 + c * 16 + cl) * 72 + quad * 8 + 32];
    }
#pragma unroll
    for (int db = 0; db < 4; ++db) {
      short8 av0 = *(const short8*)&Vs[(db * 16 + cl) * 72 + quad * 8];
      short8 av1 = *(const short8*)&Vs[(db * 16 + cl) * 72 + quad * 8 + 32];
#pragma unroll
      for (int c = 0; c < 2; ++c) {
        o[c][db] = __builtin_amdgcn_mfma_f32_16x16x32_bf16(av0, bp[c][0], o[c][db], 0, 0, 0);
        o[c][db] = __builtin_amdgcn_mfma_f32_16x16x32_bf16(av1, bp[c][1], o[c][db], 0, 0, 0);
      }
    }
  }

  // store partials
#pragma unroll
  for (int c = 0; c < 2; ++c) {
    const int rp = z * 65536 + y * 2048 + n0 + q0 + c * 16 + cl;
#pragma unroll
    for (int db = 0; db < 4; ++db) {
      ushort4 st;
      st.x = f2bf(o[c][db][0]); st.y = f2bf(o[c][db][1]);
      st.z = f2bf(o[c][db][2]); st.w = f2bf(o[c][db][3]);
      *(ushort4*)(Po + (size_t)rp * 64 + db * 16 + quad * 4) = st;
    }
    if (quad == 0) { Pl[rp] = l_r[c]; }
  }
}

// combine the 2 K-split partials (exact, no max) -> bf16 unheads output
__global__ __launch_bounds__(256) void attn_combine_kernel(
    const u16* __restrict__ Po, const float* __restrict__ Pl,
    u16* __restrict__ Ou)
{
  const int rowi = blockIdx.x * 4 + (threadIdx.x >> 6);
  const int lane = threadIdx.x & 63;
  const float l0 = Pl[rowi], l1 = Pl[65536 + rowi];
  const float inv = 1.f / (l0 + l1);
  const float o0 = bf2f(Po[(size_t)rowi * 64 + lane]);
  const float o1 = bf2f(Po[(size_t)65536 * 64 + (size_t)rowi * 64 + lane]);
  const float val = (o0 + o1) * inv;
  const int y = rowi >> 11, q = rowi & 2047;
  const int bz = y >> 2, h = y & 3;
  Ou[(size_t)(bz * NTOK + q) * 256 + h * 64 + lane] = f2bf(val);
}

// ---------------------------------------------------------------------------
// LayerNorm + exact GELU, bf16 in (M2,512) -> bf16 out
// ---------------------------------------------------------------------------
__global__ __launch_bounds__(256) void ln_gelu_kernel(
    const u16* __restrict__ Hm, const float* __restrict__ g,
    const float* __restrict__ be, u16* __restrict__ out)
{
  const int rowi = blockIdx.x * 4 + (threadIdx.x >> 6);
  const int lane = threadIdx.x & 63;
  const u16* row = Hm + (size_t)rowi * 512 + lane * 8;
  u16* orow = out + (size_t)rowi * 512 + lane * 8;
  uint4 raw = *(const uint4*)row;
  float x[8];
  const unsigned* rw = (const unsigned*)&raw;
#pragma unroll
  for (int i = 0; i < 4; ++i) {
    x[2 * i]     = bf2f((u16)rw[i]);
    x[2 * i + 1] = bf2f((u16)(rw[i] >> 16));
  }
  float s = 0.f;
#pragma unroll
  for (int i = 0; i < 8; ++i) s += x[i];
#pragma unroll
  for (int off = 32; off; off >>= 1) s += __shfl_xor(s, off);
  const float mean = s * (1.f / 512.f);
  float s2 = 0.f;
#pragma unroll
  for (int i = 0; i < 8; ++i) { const float d = x[i] - mean; s2 += d * d; }
#pragma unroll
  for (int off = 32; off; off >>= 1) s2 += __shfl_xor(s2, off);
  const float rstd = rsqrtf(s2 * (1.f / 512.f) + 1e-5f);
  unsigned ov[4];
#pragma unroll
  for (int i = 0; i < 4; ++i) {
    const int c = lane * 8 + 2 * i;
    const float y0 = (x[2 * i] - mean) * rstd * g[c] + be[c];
    const float y1 = (x[2 * i + 1] - mean) * rstd * g[c + 1] + be[c + 1];
    const float g0 = 0.5f * y0 * (1.f + erff(y0 * 0.70710678118654752f));
    const float g1 = 0.5f * y1 * (1.f + erff(y1 * 0.70710678118654752f));
    ov[i] = (unsigned)f2bf(g0) | ((unsigned)f2bf(g1) << 16);
  }
  *(uint4*)orow = *(uint4*)ov;
}

// ---------------------------------------------------------------------------
// pack everything fp32 -> bf16: 5 weight mats (589824 elems) + 2 descs.
// ---------------------------------------------------------------------------
__global__ __launch_bounds__(256) void pack_all_kernel(
    const float* w0, const float* w1, const float* w2, const float* w3,
    const float* w4, const float* d0, const float* d1,
    u16* __restrict__ wb, u16* __restrict__ descb)
{
  const size_t idx4 = ((size_t)blockIdx.x * 256 + threadIdx.x) * 4;
  const float* src; u16* dst; size_t off;
  if (idx4 < 589824) {
    off = idx4; dst = wb + idx4;
    if      (idx4 < 196608) { src = w0; }
    else if (idx4 < 327680) { src = w1; off -= 196608; }
    else if (idx4 < 393216) { src = w2; off -= 327680; }
    else if (idx4 < 458752) { src = w3; off -= 393216; }
    else                    { src = w4; off -= 458752; }
  } else {
    size_t o = idx4 - 589824;
    dst = descb + o;
    if (o < NMu) { src = d0; off = o; }
    else         { src = d1; off = o - NMu; }
  }
  float4 v = *(const float4*)(src + off);
  ushort4 ov;
  ov.x = f2bf(v.x); ov.y = f2bf(v.y); ov.z = f2bf(v.z); ov.w = f2bf(v.w);
  *(ushort4*)dst = ov;
}

// ---------------------------------------------------------------------------
extern "C" void kernel_launch(void* const* d_in, const int* in_sizes, int n_in,
                              void* d_out, int out_size, void* d_ws, size_t ws_size,
                              hipStream_t stream) {
  const float* desc0  = (const float*)d_in[0];
  const float* desc1  = (const float*)d_in[1];
  const float* enc0   = (const float*)d_in[2];
  const float* enc1   = (const float*)d_in[3];
  const float* s_Wqkv = (const float*)d_in[4];
  const float* s_bqkv = (const float*)d_in[5];
  const float* s_Wout = (const float*)d_in[6];
  const float* s_bout = (const float*)d_in[7];
  const float* s_W1   = (const float*)d_in[8];
  const float* s_b1   = (const float*)d_in[9];
  const float* s_g    = (const float*)d_in[10];
  const float* s_be   = (const float*)d_in[11];
  const float* s_W2   = (const float*)d_in[12];
  const float* s_b2   = (const float*)d_in[13];
  const float* c_Wqk  = (const float*)d_in[14];
  const float* c_bqk  = (const float*)d_in[15];
  const float* c_Wv   = (const float*)d_in[16];
  const float* c_bv   = (const float*)d_in[17];
  const float* c_Wo   = (const float*)d_in[18];
  const float* c_bo   = (const float*)d_in[19];
  const float* c_W1   = (const float*)d_in[20];
  const float* c_b1   = (const float*)d_in[21];
  const float* c_g    = (const float*)d_in[22];
  const float* c_be   = (const float*)d_in[23];
  const float* c_W2   = (const float*)d_in[24];
  const float* c_b2   = (const float*)d_in[25];

  u16* U = (u16*)d_ws;
  u16* descb = U + 0 * NMu;             // [all]
  u16* qkvb  = U + 2 * NMu;             // 6u, phase A only
  u16* ctxb  = U + 2 * NMu;             // 2u, combine out (self B / cross E)
  u16* Qu    = U + 8 * NMu;             // self Q / cross qkb
  u16* Ku    = U + 10 * NMu;            // self K / cross vb
  u16* Vu    = U + 12 * NMu;            // self V staging
  u16* Vt    = U + 14 * NMu;            // transposed V
  u16* hbufb = U + 12 * NMu;            // 4u ffn hidden (after attn)
  u16* Po    = U + 16 * NMu;            // 4u attn partials
  u16* hb2   = U + 16 * NMu;            // 4u ln out (after combine)
  float* Pl  = (float*)(U + 20 * NMu);
  float* b1f = Pl + 2 * 65536;          // 512 fp32
  float* cb1f = b1f + 512;
  u16* s_b   = U + 21 * NMu;            // self outputs
  u16* wb    = U + 23 * NMu;

  u16* Wqkvb = wb;                      // 196608
  u16* W2b   = wb + 196608;             // 131072
  u16* cQKVb = wb + 327680;             // cWqk(65536) || cWv(65536)
  u16* cW2b  = wb + 458752;             // 131072
  u16* W1f   = wb + 589824;             // 262144 (fused self FFN1 weight)
  u16* cW1f  = wb + 851968;             // 262144

  float* outf = (float*)d_out;

  const dim3 attn_grid(NTOK / 128, 32, 2);
  const dim3 tv_grid(NTOK / 64, NHEAD, 8);
  const int rope_blocks = (M2 * 128) / 256;
  const int lng_blocks  = M2 / 4;
  const int comb_blocks = 65536 / 4;
  const float csc = 0.42466090014400953f;  // 8^-0.5 * sqrt(log2 e)

  // 1. pack weights + descs
  hipLaunchKernelGGL(pack_all_kernel, dim3(4672), dim3(256), 0, stream,
                     s_Wqkv, s_W2, c_Wqk, c_Wv, c_W2, desc0, desc1, wb, descb);
  // 2. fold Wout->W1, cWo->cW1 (+bias folds)
  hipLaunchKernelGGL(wfuse_kernel, dim3(512, 2), dim3(256), 0, stream,
                     s_W1, s_Wout, s_b1, s_bout, c_W1, c_Wo, c_b1, c_bo,
                     W1f, cW1f, b1f, cb1f);

  // ---------------- self blocks (batched) ----------------
  // 3. qkv GEMM
  hipLaunchKernelGGL(gemm_bf16_kernel, dim3(6, 128), dim3(256), 0, stream,
                     descb, 256, (const u16*)nullptr, 0, 1 << 30, Wqkvb,
                     s_bqkv, (const float*)nullptr, 1 << 30, 1.f, 1.f,
                     qkvb, 768, (u16*)nullptr, 0, 256);
  // 4. rope
  hipLaunchKernelGGL(rope_repack_kernel, dim3(rope_blocks), dim3(256), 0, stream,
                     qkvb, enc0, enc1, Qu, Ku, Vu);
  // 5. transpose V
  hipLaunchKernelGGL(transpose_v_kernel, tv_grid, dim3(256), 0, stream, Vu, Vt);
  // 6/7. attention + combine
  hipLaunchKernelGGL(attn3_kernel, attn_grid, dim3(256), 0, stream,
                     Qu, Ku, Vt, Po, Pl, 0);
  hipLaunchKernelGGL(attn_combine_kernel, dim3(comb_blocks), dim3(256), 0, stream,
                     Po, Pl, ctxb);
  // 8. FFN1 (fused Wout): A=[descb | ctxb] @ W1f^T + b1f
  hipLaunchKernelGGL(gemm_bf16_kernel, dim3(4, 128), dim3(256), 0, stream,
                     descb, 256, ctxb, 256, 256, W1f,
                     b1f, (const float*)nullptr, 1 << 30, 1.f, 1.f,
                     hbufb, 512, (u16*)nullptr, 0, 512);
  // 9. LN + GELU
  hipLaunchKernelGGL(ln_gelu_kernel, dim3(lng_blocks), dim3(256), 0, stream,
                     hbufb, s_g, s_be, hb2);
  // 10. W2 + residual
  hipLaunchKernelGGL(gemm64_kernel, dim3(4, 256), dim3(256), 0, stream,
                     hb2, 512, W2b, s_b2, descb, 256,
                     (float*)nullptr, 0, s_b, 256, 512);

  // ---------------- cross block (batched) ----------------
  u16* qkb = Qu;
  u16* vb  = Ku;
  // 11. fused qk|v projection (per-half bias/scale/output)
  hipLaunchKernelGGL(gemm_bf16_kernel, dim3(4, 128), dim3(256), 0, stream,
                     s_b, 256, (const u16*)nullptr, 0, 1 << 30, cQKVb,
                     c_bqk, c_bv, 256, csc, 1.f,
                     qkb, 256, vb, 256, 256);
  // 12. transpose V
  hipLaunchKernelGGL(transpose_v_kernel, tv_grid, dim3(256), 0, stream, vb, Vt);
  // 13/14. attention + combine
  hipLaunchKernelGGL(attn3_kernel, attn_grid, dim3(256), 0, stream,
                     qkb, qkb, Vt, Po, Pl, 1);
  hipLaunchKernelGGL(attn_combine_kernel, dim3(comb_blocks), dim3(256), 0, stream,
                     Po, Pl, ctxb);
  // 15. FFN1 (fused cWo)
  hipLaunchKernelGGL(gemm_bf16_kernel, dim3(4, 128), dim3(256), 0, stream,
                     s_b, 256, ctxb, 256, 256, cW1f,
                     cb1f, (const float*)nullptr, 1 << 30, 1.f, 1.f,
                     hbufb, 512, (u16*)nullptr, 0, 512);
  // 16. LN + GELU
  hipLaunchKernelGGL(ln_gelu_kernel, dim3(lng_blocks), dim3(256), 0, stream,
                     hbufb, c_g, c_be, hb2);
  // 17. W2 + residual -> fp32 output
  hipLaunchKernelGGL(gemm64_kernel, dim3(4, 256), dim3(256), 0, stream,
                     hb2, 512, cW2b, c_b2, s_b, 256,
                     outf, 256, (u16*)nullptr, 0, 512);
}